// Round 6
// baseline (1221.141 us; speedup 1.0000x reference)
//
#include <hip/hip_runtime.h>
#include <stdint.h>

// ---------------------------------------------------------------------------
// TimeAwareIMULSTMEncoder on MI355X (gfx950) — round 6
// vs round 5:
//  * k_xg_gemm DELETED. xg (x@Wih+bias) is now computed inside the scan,
//    per 5-step chunk, into MFMA accumulators (80 AGPRs). Kills 131 MB
//    HBM write + 131 MB read + 3 GEMM dispatches (~150 us).
//  * scan re-tiled: 10 seqs/block -> 128 blocks/dir x 2 dirs = 256 blocks
//    = 1 block on EVERY CU (was 160/256). Per-CU pointwise drops 1.6x.
//  * A (prev-layer Y) staged per chunk via global_load_lds in MFMA-lane
//    order (conflict-free b128 reads); Wih^T B-frags streamed from L2.
// ---------------------------------------------------------------------------

typedef unsigned short ushort_t;
typedef short short8 __attribute__((ext_vector_type(8)));     // 8 bf16 (4 VGPRs)
typedef float float4v __attribute__((ext_vector_type(4)));    // MFMA acc

#define DEV_INLINE __device__ __forceinline__

DEV_INLINE ushort_t f2bf(float f) {                 // RNE f32 -> bf16 bits
  union { float f; unsigned u; } v; v.f = f;
  unsigned r = v.u + 0x7fffu + ((v.u >> 16) & 1u);
  return (ushort_t)(r >> 16);
}
DEV_INLINE float bf2f(ushort_t s) {
  union { unsigned u; float f; } v; v.u = ((unsigned)s) << 16;
  return v.f;
}
DEV_INLINE float sigmoidf_(float x) {
  return __builtin_amdgcn_rcpf(1.0f + __expf(-x));
}
DEV_INLINE float tanhf_(float x) {                  // 1 - 2/(1+e^{2x}); safe at +-inf
  return 1.0f - 2.0f * __builtin_amdgcn_rcpf(1.0f + __expf(2.0f * x));
}

// async global->LDS, 16B per lane; dst must be wave-uniform base + lane*16.
DEV_INLINE void gload16(const ushort_t* g, ushort_t* l) {
  __builtin_amdgcn_global_load_lds(
      (const __attribute__((address_space(1))) unsigned int*)g,
      (__attribute__((address_space(3))) unsigned int*)l, 16, 0, 0);
}

// --------------------------- weight prep (tiled transpose) ------------------
// WT arena (elements):
//   Wih0 @0 [2*512*64] | Wih1 @65536 [2*512*256] | Wih2 @327680 [2*512*256]
//   Whh0 @589824 | Whh1 @720896 | Whh2 @851968 (each [2*512*128])
//   W1T  @983040 [512*768] | W2T @1376256 [256*512]
__global__ __launch_bounds__(256) void k_prep(
    const float* __restrict__ Wih0, const float* __restrict__ Wih1,
    const float* __restrict__ Wih2, const float* __restrict__ Whh0,
    const float* __restrict__ Whh1, const float* __restrict__ Whh2,
    const float* __restrict__ Wout1, const float* __restrict__ Wout2,
    ushort_t* __restrict__ WT)
{
  __shared__ float T[32][65];
  const int b = blockIdx.x;
  const int tid = threadIdx.x;
  const float* S; int Kd, C; size_t dstBase; int kt, nt;
  if (b < 32) {
    int rel = b; int d = (rel >> 3) / 2; kt = (rel >> 3) & 1; nt = rel & 7;
    S = Wih0 + (size_t)d * 64 * 512; C = 512; Kd = 64;
    dstBase = 0 + (size_t)d * 512 * 64;
  } else if (b < 160) {
    int rel = b - 32; int d = (rel >> 3) / 8; kt = (rel >> 3) & 7; nt = rel & 7;
    S = Wih1 + (size_t)d * 256 * 512; C = 512; Kd = 256;
    dstBase = 65536 + (size_t)d * 512 * 256;
  } else if (b < 288) {
    int rel = b - 160; int d = (rel >> 3) / 8; kt = (rel >> 3) & 7; nt = rel & 7;
    S = Wih2 + (size_t)d * 256 * 512; C = 512; Kd = 256;
    dstBase = 327680 + (size_t)d * 512 * 256;
  } else if (b < 352) {
    int rel = b - 288; int d = (rel >> 3) / 4; kt = (rel >> 3) & 3; nt = rel & 7;
    S = Whh0 + (size_t)d * 128 * 512; C = 512; Kd = 128;
    dstBase = 589824 + (size_t)d * 512 * 128;
  } else if (b < 416) {
    int rel = b - 352; int d = (rel >> 3) / 4; kt = (rel >> 3) & 3; nt = rel & 7;
    S = Whh1 + (size_t)d * 128 * 512; C = 512; Kd = 128;
    dstBase = 720896 + (size_t)d * 512 * 128;
  } else if (b < 480) {
    int rel = b - 416; int d = (rel >> 3) / 4; kt = (rel >> 3) & 3; nt = rel & 7;
    S = Whh2 + (size_t)d * 128 * 512; C = 512; Kd = 128;
    dstBase = 851968 + (size_t)d * 512 * 128;
  } else if (b < 672) {
    int rel = b - 480; kt = rel >> 3; nt = rel & 7;
    S = Wout1; C = 512; Kd = 768; dstBase = 983040;
  } else {
    int rel = b - 672; kt = rel >> 2; nt = rel & 3;
    S = Wout2; C = 256; Kd = 512; dstBase = 1376256;
  }
  const int k0 = kt * 32, n0 = nt * 64;
  {
    int kr = tid >> 6;                // 0..3
    int n  = tid & 63;
#pragma unroll
    for (int i = 0; i < 8; i++)
      T[i * 4 + kr][n] = S[(size_t)(k0 + i * 4 + kr) * C + n0 + n];
  }
  __syncthreads();
  {
    int n = tid >> 2;                 // 0..63
    int ko = (tid & 3) * 8;           // 0,8,16,24
    ushort_t pk[8];
#pragma unroll
    for (int j = 0; j < 8; j++) pk[j] = f2bf(T[ko + j][n]);
    *(uint4*)(WT + dstBase + (size_t)(n0 + n) * Kd + k0 + ko) = *(uint4*)pk;
  }
}

// --------------------------- input projection ------------------------------
__global__ __launch_bounds__(256) void k_inproj(
    const float* __restrict__ imu, const float* __restrict__ W_in,
    const float* __restrict__ b_in, ushort_t* __restrict__ act0)
{
  int idx = blockIdx.x * 256 + threadIdx.x;   // 64000*64 exactly
  int j = idx & 63, r = idx >> 6;
  int l = r % 50;
  const float* x = imu + (size_t)r * 6;
  float acc = b_in[j];
#pragma unroll
  for (int d = 0; d < 6; d++) acc += x[d] * W_in[d * 64 + j];
  acc += (l * (1.0f / 49.0f)) * W_in[6 * 64 + j] + W_in[7 * 64 + j]; // t, rate=1
  act0[idx] = f2bf(fmaxf(acc, 0.0f));
}

// --------------------------- fused GEMM + LSTM scan -------------------------
// Block: 10 seqs of one direction, 512 thr / 8 waves, 1 block/CU.
// Per chunk of 5 timesteps:
//   stage A (prev-layer rows, MFMA-lane order) via global_load_lds, 1 barrier;
//   chunk xg GEMM: accx[5][4] = bias + x_t @ Wih  (B-frags from L2);
//   5 recurrence steps: h@Whh MFMA (frags in VGPRs) + accx -> LDS P[cell][4]
//   -> pointwise (2.5 cells/lane) -> h to dbuf hbuf. 2 barriers/step.
// MODE 0: write Y. MODE 1: fused mean/max/final aggregation (bf16 agg).
template <int K, int MODE>
__global__ __launch_bounds__(512, 2) void k_fscan(
    const ushort_t* __restrict__ Xprev,  // [64000][K] bf16 (rows seq*50+t)
    const ushort_t* __restrict__ WihT,   // [2][512][K] bf16 n-major
    const ushort_t* __restrict__ WhhT,   // [2][512][128] bf16 n-major
    const float* __restrict__ bih, const float* __restrict__ bhh, // [2][512]
    ushort_t* __restrict__ Y,            // [64000][256] bf16
    ushort_t* __restrict__ aggb)         // [1280][768] bf16
{
  constexpr int KT = K / 32;
  __shared__ __align__(16) ushort_t Abuf[5 * KT * 512];  // K=256: 40 KiB
  __shared__ __align__(16) float P[1280 * 4];            // 20 KiB
  __shared__ __align__(16) ushort_t hbuf[2][16][136];    // 8.5 KiB

  const int dir = blockIdx.y;
  const int s0 = blockIdx.x * 10;
  const int tid = threadIdx.x;
  const int wave = tid >> 6, lane = tid & 63;
  const int cl = lane & 15, quad = lane >> 4;

  // wave owns gate-cols wave*64 + n*16 + cl (n = 0..3)
  int colv[4], gatev[4], hcv[4];
  float biasv[4];
  short8 Bhh[4][4];
#pragma unroll
  for (int n = 0; n < 4; n++) {
    colv[n] = wave * 64 + n * 16 + cl;
    gatev[n] = colv[n] >> 7;
    hcv[n] = colv[n] & 127;
    biasv[n] = bih[dir * 512 + colv[n]] + bhh[dir * 512 + colv[n]];
#pragma unroll
    for (int kt = 0; kt < 4; kt++)
      Bhh[n][kt] = *(const short8*)(WhhT + ((size_t)dir * 512 + colv[n]) * 128 + kt * 32 + quad * 8);
  }

  float cst[3] = {0.f, 0.f, 0.f};
  float sum[3] = {0.f, 0.f, 0.f};
  float mx[3]  = {-3.0e38f, -3.0e38f, -3.0e38f};
  float hL[3]  = {0.f, 0.f, 0.f};
  ushort_t pend[3] = {0, 0, 0};
  int tPrev = 0;

  for (int i = tid; i < 2 * 16 * 136; i += 512) ((ushort_t*)hbuf)[i] = 0;

  const int arow = (s0 + (cl < 10 ? cl : 9)) * 50;   // clamp pad rows to valid mem

  for (int chunk = 0; chunk < 10; chunk++) {
    const int ch5 = chunk * 5;

    // ---- stage chunk A: block-unit bu covers (ts,kt); lane = MFMA (cl,quad) ----
    constexpr int NI = (5 * KT + 7) / 8;
#pragma unroll
    for (int i = 0; i < NI; i++) {
      int bu = i * 8 + wave;
      if (bu < 5 * KT) {
        int ts = bu / KT, kt = bu % KT;
        int t = dir ? 49 - (ch5 + ts) : (ch5 + ts);
        gload16(Xprev + (size_t)(arow + t) * K + kt * 32 + quad * 8,
                Abuf + bu * 512 + lane * 8);
      }
    }
    __syncthreads();                   // A ready (also drains pend Y stores)

    // ---- chunk xg GEMM: accx[ts][n] = bias + x_t @ Wih ----
    float4v accx[5][4];
#pragma unroll
    for (int ts = 0; ts < 5; ts++)
#pragma unroll
      for (int n = 0; n < 4; n++)
        accx[ts][n] = float4v{biasv[n], biasv[n], biasv[n], biasv[n]};
#pragma unroll
    for (int kt = 0; kt < KT; kt++) {
      short8 Bx[4];
#pragma unroll
      for (int n = 0; n < 4; n++)
        Bx[n] = *(const short8*)(WihT + ((size_t)dir * 512 + colv[n]) * K + kt * 32 + quad * 8);
#pragma unroll
      for (int ts = 0; ts < 5; ts++) {
        short8 Ax = *(const short8*)(Abuf + (ts * KT + kt) * 512 + lane * 8);
#pragma unroll
        for (int n = 0; n < 4; n++)
          accx[ts][n] = __builtin_amdgcn_mfma_f32_16x16x32_bf16(Ax, Bx[n], accx[ts][n], 0, 0, 0);
      }
    }

    // ---- 5 recurrence steps ----
#pragma unroll
    for (int ts = 0; ts < 5; ts++) {
      const int step = ch5 + ts;
      const int cur = step & 1;
      const int t = dir ? 49 - step : step;

      if (MODE == 0 && step > 0) {     // flush previous step's Y
#pragma unroll
        for (int j = 0; j < 2; j++) {
          int c = tid + j * 512;
          Y[((size_t)(s0 + (c >> 7)) * 50 + tPrev) * 256 + dir * 128 + (c & 127)] = pend[j];
        }
        if (tid < 256) {
          int c = tid + 1024;
          Y[((size_t)(s0 + (c >> 7)) * 50 + tPrev) * 256 + dir * 128 + (c & 127)] = pend[2];
        }
      }

      short8 Ah[4];
#pragma unroll
      for (int kt = 0; kt < 4; kt++)   // A: m=lane&15 (=seq), k=quad*8+j
        Ah[kt] = *(const short8*)(&hbuf[cur][cl][kt * 32 + quad * 8]);
      float4v acch[4];
#pragma unroll
      for (int n = 0; n < 4; n++) acch[n] = float4v{0.f, 0.f, 0.f, 0.f};
#pragma unroll
      for (int kt = 0; kt < 4; kt++)
#pragma unroll
        for (int n = 0; n < 4; n++)
          acch[n] = __builtin_amdgcn_mfma_f32_16x16x32_bf16(Ah[kt], Bhh[n][kt], acch[n], 0, 0, 0);

#pragma unroll
      for (int n = 0; n < 4; n++)
#pragma unroll
        for (int r = 0; r < 4; r++) {
          int seq = quad * 4 + r;      // C: row=quad*4+r, col=lane&15
          if (seq < 10)
            P[((seq << 7) + hcv[n]) * 4 + gatev[n]] = acch[n][r] + accx[ts][n][r];
        }
      __syncthreads();                 // gate sums visible

      auto cellDo = [&](int c, int j) {
        float4v g4 = *(const float4v*)(P + c * 4);
        float ii = sigmoidf_(g4[0]);
        float ff = sigmoidf_(g4[1]);
        float gc = tanhf_(g4[2]);
        float oo = sigmoidf_(g4[3]);
        float c2 = ff * cst[j] + ii * gc;
        cst[j] = c2;
        float h = oo * tanhf_(c2);
        ushort_t hb = f2bf(h);
        hbuf[cur ^ 1][c >> 7][c & 127] = hb;
        if (MODE == 0) {
          pend[j] = hb;
        } else {
          sum[j] += h;
          mx[j] = fmaxf(mx[j], h);
          hL[j] = h;
        }
      };
      cellDo(tid, 0);
      cellDo(tid + 512, 1);
      if (tid < 256) cellDo(tid + 1024, 2);

      tPrev = t;
      __syncthreads();                 // h visible; P reusable
    }
  }

  if (MODE == 0) {
#pragma unroll
    for (int j = 0; j < 2; j++) {
      int c = tid + j * 512;
      Y[((size_t)(s0 + (c >> 7)) * 50 + tPrev) * 256 + dir * 128 + (c & 127)] = pend[j];
    }
    if (tid < 256) {
      int c = tid + 1024;
      Y[((size_t)(s0 + (c >> 7)) * 50 + tPrev) * 256 + dir * 128 + (c & 127)] = pend[2];
    }
  } else {
    auto aggDo = [&](int c, int j) {
      int seq = s0 + (c >> 7), cc = dir * 128 + (c & 127);
      aggb[(size_t)seq * 768 + cc]       = f2bf(sum[j] * (1.0f / 50.0f));
      aggb[(size_t)seq * 768 + 256 + cc] = f2bf(mx[j]);
      aggb[(size_t)seq * 768 + 512 + cc] = f2bf(hL[j]);   // h_n of this dir
    };
    aggDo(tid, 0);
    aggDo(tid + 512, 1);
    if (tid < 256) aggDo(tid + 1024, 2);
  }
}

// --------------------------- fused head -------------------------------------
__global__ __launch_bounds__(512, 1) void k_head(
    const ushort_t* __restrict__ aggb,  // [1280][768] bf16
    const ushort_t* __restrict__ W1T,   // [512][768] bf16
    const float* __restrict__ b1, const float* __restrict__ ln_g,
    const float* __restrict__ ln_b,
    const ushort_t* __restrict__ W2T,   // [256][512] bf16
    const float* __restrict__ b2, float* __restrict__ out) // [1280][256]
{
  __shared__ __align__(16) char smem[78336];
  ushort_t* AsB = (ushort_t*)smem;            // [2][64*32]   (8 KiB)
  ushort_t* BsB = (ushort_t*)(smem + 8192);   // [2][512*32]  (64 KiB)
  ushort_t* hn  = (ushort_t*)smem;            // [64][520] aliased (66.6 KiB)
  float* partS  = (float*)(smem + 73728);     // [64][8]
  float* partQ  = partS + 512;                // [64][8]
  float* muS    = partQ + 512;                // [64]
  float* rsS    = muS + 64;                   // [64]

  const int m0 = blockIdx.x * 64;
  const int tid = threadIdx.x;
  const int wave = tid >> 6, lane = tid & 63;
  const int cl = lane & 15, quad = lane >> 4;
  const int srow = lane >> 2, scol = (lane & 3) * 8;

  float4v acc1[4][4];
#pragma unroll
  for (int i = 0; i < 4; i++)
#pragma unroll
    for (int v = 0; v < 4; v++) acc1[i][v] = float4v{0.f, 0.f, 0.f, 0.f};

#define STAGE1(buf, kb)                                                       \
  {                                                                           \
    if (wave < 4)                                                             \
      gload16(aggb + (size_t)(m0 + wave * 16 + srow) * 768 + (kb) + scol,     \
              AsB + (buf) * 2048 + wave * 16 * 32 + lane * 8);                \
    _Pragma("unroll")                                                         \
    for (int j = 0; j < 4; j++)                                               \
      gload16(W1T + (size_t)(wave * 64 + j * 16 + srow) * 768 + (kb) + scol,  \
              BsB + (buf) * 16384 + (wave * 64 + j * 16) * 32 + lane * 8);    \
  }

  STAGE1(0, 0)
  for (int kb = 0; kb < 768; kb += 32) {
    const int cur = (kb >> 5) & 1;
    __syncthreads();
    if (kb + 32 < 768) STAGE1(cur ^ 1, kb + 32)
    short8 Af[4], Bf[4];
#pragma unroll
    for (int i = 0; i < 4; i++)
      Af[i] = *(const short8*)(AsB + cur * 2048 + (i * 16 + cl) * 32 + quad * 8);
#pragma unroll
    for (int v = 0; v < 4; v++)
      Bf[v] = *(const short8*)(BsB + cur * 16384 + (wave * 64 + v * 16 + cl) * 32 + quad * 8);
#pragma unroll
    for (int i = 0; i < 4; i++)
#pragma unroll
      for (int v = 0; v < 4; v++)
        acc1[i][v] = __builtin_amdgcn_mfma_f32_16x16x32_bf16(Af[i], Bf[v], acc1[i][v], 0, 0, 0);
  }
#undef STAGE1
  __syncthreads();          // all waves done with AsB/BsB (hn aliases them)

  float bcol[4], lg[4], lb[4];
#pragma unroll
  for (int v = 0; v < 4; v++) {
    int col = wave * 64 + v * 16 + cl;
    bcol[v] = b1[col]; lg[v] = ln_g[col]; lb[v] = ln_b[col];
  }

#pragma unroll
  for (int i = 0; i < 4; i++) {
#pragma unroll
    for (int r = 0; r < 4; r++) {
      float s = 0.f, q = 0.f;
#pragma unroll
      for (int v = 0; v < 4; v++) {
        float x = acc1[i][v][r] + bcol[v];
        s += x; q += x * x;
      }
#pragma unroll
      for (int m = 1; m <= 8; m <<= 1) {
        s += __shfl_xor(s, m);
        q += __shfl_xor(q, m);
      }
      if (cl == 0) {
        int row = i * 16 + quad * 4 + r;
        partS[row * 8 + wave] = s;
        partQ[row * 8 + wave] = q;
      }
    }
  }
  __syncthreads();
  if (tid < 64) {
    float s = 0.f, q = 0.f;
#pragma unroll
    for (int w = 0; w < 8; w++) { s += partS[tid * 8 + w]; q += partQ[tid * 8 + w]; }
    float mu = s * (1.0f / 512.0f);
    float var = q * (1.0f / 512.0f) - mu * mu;
    muS[tid] = mu;
    rsS[tid] = rsqrtf(var + 1e-5f);
  }
  __syncthreads();

#pragma unroll
  for (int i = 0; i < 4; i++) {
#pragma unroll
    for (int r = 0; r < 4; r++) {
      int row = i * 16 + quad * 4 + r;
      float mu = muS[row], rs = rsS[row];
#pragma unroll
      for (int v = 0; v < 4; v++) {
        int col = wave * 64 + v * 16 + cl;
        float x = acc1[i][v][r] + bcol[v];
        float y = (x - mu) * rs * lg[v] + lb[v];
        hn[row * 520 + col] = f2bf(fmaxf(y, 0.0f));
      }
    }
  }
  __syncthreads();

  float4v acc2[4][2];
#pragma unroll
  for (int i = 0; i < 4; i++)
#pragma unroll
    for (int u = 0; u < 2; u++) acc2[i][u] = float4v{0.f, 0.f, 0.f, 0.f};
  for (int kt = 0; kt < 16; kt++) {
    short8 Af2[4], Bf2[2];
#pragma unroll
    for (int u = 0; u < 2; u++)
      Bf2[u] = *(const short8*)(W2T + (size_t)(wave * 32 + u * 16 + cl) * 512 + kt * 32 + quad * 8);
#pragma unroll
    for (int i = 0; i < 4; i++)
      Af2[i] = *(const short8*)(hn + (i * 16 + cl) * 520 + kt * 32 + quad * 8);
#pragma unroll
    for (int i = 0; i < 4; i++)
#pragma unroll
      for (int u = 0; u < 2; u++)
        acc2[i][u] = __builtin_amdgcn_mfma_f32_16x16x32_bf16(Af2[i], Bf2[u], acc2[i][u], 0, 0, 0);
  }
#pragma unroll
  for (int u = 0; u < 2; u++) {
    int col = wave * 32 + u * 16 + cl;
    float bb = b2[col];
#pragma unroll
    for (int i = 0; i < 4; i++)
#pragma unroll
      for (int r = 0; r < 4; r++)
        out[(size_t)(m0 + i * 16 + quad * 4 + r) * 256 + col] = acc2[i][u][r] + bb;
  }
}

// --------------------------- launcher --------------------------------------
extern "C" void kernel_launch(void* const* d_in, const int* in_sizes, int n_in,
                              void* d_out, int out_size, void* d_ws, size_t ws_size,
                              hipStream_t stream)
{
  (void)in_sizes; (void)n_in; (void)out_size; (void)ws_size;
  const float* imu   = (const float*)d_in[0];
  const float* W_in  = (const float*)d_in[1];
  const float* b_in  = (const float*)d_in[2];
  const float* Wih0  = (const float*)d_in[3];
  const float* Whh0  = (const float*)d_in[4];
  const float* bih0  = (const float*)d_in[5];
  const float* bhh0  = (const float*)d_in[6];
  const float* Wih1  = (const float*)d_in[7];
  const float* Whh1  = (const float*)d_in[8];
  const float* bih1  = (const float*)d_in[9];
  const float* bhh1  = (const float*)d_in[10];
  const float* Wih2  = (const float*)d_in[11];
  const float* Whh2  = (const float*)d_in[12];
  const float* bih2  = (const float*)d_in[13];
  const float* bhh2  = (const float*)d_in[14];
  const float* Wout1 = (const float*)d_in[15];
  const float* bout1 = (const float*)d_in[16];
  const float* ln_g  = (const float*)d_in[17];
  const float* ln_b  = (const float*)d_in[18];
  const float* Wout2 = (const float*)d_in[19];
  const float* bout2 = (const float*)d_in[20];
  float* out = (float*)d_out;
  char* ws = (char*)d_ws;

  // ws layout (bytes): act0 @0 (8.19 MB) | Ya @8192000 (32.77 MB)
  //                  | Yb @40960000 (32.77 MB) | WT @73728000 (3.01 MB)
  // aggb reuses act0 region (act0 dead after layer 0; aggb written layer 2).
  ushort_t* act0 = (ushort_t*)(ws + 0);
  ushort_t* Ya   = (ushort_t*)(ws + 8192000);
  ushort_t* Yb   = (ushort_t*)(ws + 40960000);
  ushort_t* WT   = (ushort_t*)(ws + 73728000);
  ushort_t* aggb = (ushort_t*)(ws + 0);

  ushort_t* WT_ih0 = WT + 0;
  ushort_t* WT_ih1 = WT + 65536;
  ushort_t* WT_ih2 = WT + 327680;
  ushort_t* WT_hh0 = WT + 589824;
  ushort_t* WT_hh1 = WT + 720896;
  ushort_t* WT_hh2 = WT + 851968;
  ushort_t* W1T    = WT + 983040;
  ushort_t* W2T    = WT + 1376256;

  k_prep<<<736, 256, 0, stream>>>(Wih0, Wih1, Wih2, Whh0, Whh1, Whh2,
                                  Wout1, Wout2, WT);
  k_inproj<<<16000, 256, 0, stream>>>(imu, W_in, b_in, act0);

  k_fscan<64, 0><<<dim3(128, 2), 512, 0, stream>>>(
      act0, WT_ih0, WT_hh0, bih0, bhh0, Ya, aggb);
  k_fscan<256, 0><<<dim3(128, 2), 512, 0, stream>>>(
      Ya, WT_ih1, WT_hh1, bih1, bhh1, Yb, aggb);
  k_fscan<256, 1><<<dim3(128, 2), 512, 0, stream>>>(
      Yb, WT_ih2, WT_hh2, bih2, bhh2, Ya, aggb);

  k_head<<<20, 512, 0, stream>>>(aggb, W1T, bout1, ln_g, ln_b, W2T, bout2, out);
}

// Round 7
// 1148.830 us; speedup vs baseline: 1.0629x; 1.0629x over previous
//
#include <hip/hip_runtime.h>
#include <stdint.h>

// ---------------------------------------------------------------------------
// TimeAwareIMULSTMEncoder on MI355X (gfx950) — round 7
// vs round 6 (fused GEMM+scan kept, staging fixed):
//  * ALL activations t-major: act0 [50][1280][64], Y [50][1280][256].
//    A-staging now reads 16x64B inside an 8KB window (waves cover full rows)
//    -> kills the 10x fetch amplification (round 6: FETCH 1.1 GB).
//  * DMA source XOR-swizzle (chunk c4^(row&3)) so the MFMA A-read
//    (cl*64B + (quad^(cl&3))*16B) is 2-way/quarter-wave = conflict-free.
//  * xg accumulated per chunk (accx[5][4] AGPRs) amortizing Wih B-frag L2
//    reads; DMA for chunk+1 issued after xg-done barrier, hidden under steps.
// ---------------------------------------------------------------------------

typedef unsigned short ushort_t;
typedef short short8 __attribute__((ext_vector_type(8)));     // 8 bf16 (4 VGPRs)
typedef float float4v __attribute__((ext_vector_type(4)));    // MFMA acc

#define DEV_INLINE __device__ __forceinline__

DEV_INLINE ushort_t f2bf(float f) {                 // RNE f32 -> bf16 bits
  union { float f; unsigned u; } v; v.f = f;
  unsigned r = v.u + 0x7fffu + ((v.u >> 16) & 1u);
  return (ushort_t)(r >> 16);
}
DEV_INLINE float bf2f(ushort_t s) {
  union { unsigned u; float f; } v; v.u = ((unsigned)s) << 16;
  return v.f;
}
DEV_INLINE float sigmoidf_(float x) {
  return __builtin_amdgcn_rcpf(1.0f + __expf(-x));
}
DEV_INLINE float tanhf_(float x) {                  // 1 - 2/(1+e^{2x}); safe at +-inf
  return 1.0f - 2.0f * __builtin_amdgcn_rcpf(1.0f + __expf(2.0f * x));
}

// async global->LDS, 16B per lane; dst must be wave-uniform base + lane*16.
DEV_INLINE void gload16(const ushort_t* g, ushort_t* l) {
  __builtin_amdgcn_global_load_lds(
      (const __attribute__((address_space(1))) unsigned int*)g,
      (__attribute__((address_space(3))) unsigned int*)l, 16, 0, 0);
}

// --------------------------- weight prep (tiled transpose) ------------------
// WT arena (elements):
//   Wih0 @0 [2*512*64] | Wih1 @65536 [2*512*256] | Wih2 @327680 [2*512*256]
//   Whh0 @589824 | Whh1 @720896 | Whh2 @851968 (each [2*512*128])
//   W1T  @983040 [512*768] | W2T @1376256 [256*512]
__global__ __launch_bounds__(256) void k_prep(
    const float* __restrict__ Wih0, const float* __restrict__ Wih1,
    const float* __restrict__ Wih2, const float* __restrict__ Whh0,
    const float* __restrict__ Whh1, const float* __restrict__ Whh2,
    const float* __restrict__ Wout1, const float* __restrict__ Wout2,
    ushort_t* __restrict__ WT)
{
  __shared__ float T[32][65];
  const int b = blockIdx.x;
  const int tid = threadIdx.x;
  const float* S; int Kd, C; size_t dstBase; int kt, nt;
  if (b < 32) {
    int rel = b; int d = (rel >> 3) / 2; kt = (rel >> 3) & 1; nt = rel & 7;
    S = Wih0 + (size_t)d * 64 * 512; C = 512; Kd = 64;
    dstBase = 0 + (size_t)d * 512 * 64;
  } else if (b < 160) {
    int rel = b - 32; int d = (rel >> 3) / 8; kt = (rel >> 3) & 7; nt = rel & 7;
    S = Wih1 + (size_t)d * 256 * 512; C = 512; Kd = 256;
    dstBase = 65536 + (size_t)d * 512 * 256;
  } else if (b < 288) {
    int rel = b - 160; int d = (rel >> 3) / 8; kt = (rel >> 3) & 7; nt = rel & 7;
    S = Wih2 + (size_t)d * 256 * 512; C = 512; Kd = 256;
    dstBase = 327680 + (size_t)d * 512 * 256;
  } else if (b < 352) {
    int rel = b - 288; int d = (rel >> 3) / 4; kt = (rel >> 3) & 3; nt = rel & 7;
    S = Whh0 + (size_t)d * 128 * 512; C = 512; Kd = 128;
    dstBase = 589824 + (size_t)d * 512 * 128;
  } else if (b < 416) {
    int rel = b - 352; int d = (rel >> 3) / 4; kt = (rel >> 3) & 3; nt = rel & 7;
    S = Whh1 + (size_t)d * 128 * 512; C = 512; Kd = 128;
    dstBase = 720896 + (size_t)d * 512 * 128;
  } else if (b < 480) {
    int rel = b - 416; int d = (rel >> 3) / 4; kt = (rel >> 3) & 3; nt = rel & 7;
    S = Whh2 + (size_t)d * 128 * 512; C = 512; Kd = 128;
    dstBase = 851968 + (size_t)d * 512 * 128;
  } else if (b < 672) {
    int rel = b - 480; kt = rel >> 3; nt = rel & 7;
    S = Wout1; C = 512; Kd = 768; dstBase = 983040;
  } else {
    int rel = b - 672; kt = rel >> 2; nt = rel & 3;
    S = Wout2; C = 256; Kd = 512; dstBase = 1376256;
  }
  const int k0 = kt * 32, n0 = nt * 64;
  {
    int kr = tid >> 6;                // 0..3
    int n  = tid & 63;
#pragma unroll
    for (int i = 0; i < 8; i++)
      T[i * 4 + kr][n] = S[(size_t)(k0 + i * 4 + kr) * C + n0 + n];
  }
  __syncthreads();
  {
    int n = tid >> 2;                 // 0..63
    int ko = (tid & 3) * 8;           // 0,8,16,24
    ushort_t pk[8];
#pragma unroll
    for (int j = 0; j < 8; j++) pk[j] = f2bf(T[ko + j][n]);
    *(uint4*)(WT + dstBase + (size_t)(n0 + n) * Kd + k0 + ko) = *(uint4*)pk;
  }
}

// --------------------------- input projection (t-major out) -----------------
__global__ __launch_bounds__(256) void k_inproj(
    const float* __restrict__ imu, const float* __restrict__ W_in,
    const float* __restrict__ b_in, ushort_t* __restrict__ act0)
{
  int idx = blockIdx.x * 256 + threadIdx.x;   // 64000*64 exactly
  int j = idx & 63, r = idx >> 6;
  int seq = r / 50, l = r - seq * 50;
  const float* x = imu + (size_t)r * 6;
  float acc = b_in[j];
#pragma unroll
  for (int d = 0; d < 6; d++) acc += x[d] * W_in[d * 64 + j];
  acc += (l * (1.0f / 49.0f)) * W_in[6 * 64 + j] + W_in[7 * 64 + j]; // t, rate=1
  act0[((size_t)l * 1280 + seq) * 64 + j] = f2bf(fmaxf(acc, 0.0f));
}

// --------------------------- fused GEMM + LSTM scan -------------------------
// Block: 10 seqs of one direction, 512 thr / 8 waves, 256 blocks = 1/CU.
// Chunk of 5 steps: [A ready] -> xg GEMM (accx[5][4], A from swizzled LDS,
// Wih B-frags from L2) -> [xg done] -> DMA chunk+1 -> 5x recurrence step
// (h@Whh MFMA, frags in VGPRs -> P exchange -> pointwise 2.5 cells/lane).
// Activations t-major: Xprev/Y rows = [t][1280][cols].
template <int K, int MODE>
__global__ __launch_bounds__(512, 2) void k_fscan(
    const ushort_t* __restrict__ Xprev,  // [50][1280][K] bf16
    const ushort_t* __restrict__ WihT,   // [2][512][K] bf16 n-major
    const ushort_t* __restrict__ WhhT,   // [2][512][128] bf16 n-major
    const float* __restrict__ bih, const float* __restrict__ bhh, // [2][512]
    ushort_t* __restrict__ Y,            // [50][1280][256] bf16
    ushort_t* __restrict__ aggb)         // [1280][768] bf16
{
  constexpr int KT = K / 32;
  constexpr int NTILE = 5 * KT;                       // tiles per chunk
  constexpr int NI = (NTILE + 7) / 8;
  __shared__ __align__(16) ushort_t Abuf[NTILE * 512]; // K=256: 40 KiB
  __shared__ __align__(16) float P[1280 * 4];          // 20 KiB
  __shared__ __align__(16) ushort_t hbuf[2][16][136];  // 8.5 KiB

  const int dir = blockIdx.y;
  const int s0 = blockIdx.x * 10;
  const int tid = threadIdx.x;
  const int wave = tid >> 6, lane = tid & 63;
  const int cl = lane & 15, quad = lane >> 4;

  // staging lane map: row = lane>>2 (clamped), c4 = lane&3, swizzled source
  const int rowc = (lane >> 2) < 10 ? (lane >> 2) : 9;
  const int c4s = (lane & 3) ^ (rowc & 3);

  // wave owns gate-cols wave*64 + n*16 + cl (n = 0..3)
  int colv[4], gatev[4], hcv[4];
  float biasv[4];
  short8 Bhh[4][4];
#pragma unroll
  for (int n = 0; n < 4; n++) {
    colv[n] = wave * 64 + n * 16 + cl;
    gatev[n] = colv[n] >> 7;
    hcv[n] = colv[n] & 127;
    biasv[n] = bih[dir * 512 + colv[n]] + bhh[dir * 512 + colv[n]];
#pragma unroll
    for (int kt = 0; kt < 4; kt++)
      Bhh[n][kt] = *(const short8*)(WhhT + ((size_t)dir * 512 + colv[n]) * 128 + kt * 32 + quad * 8);
  }

  float cst[3] = {0.f, 0.f, 0.f};
  float sum[3] = {0.f, 0.f, 0.f};
  float mx[3]  = {-3.0e38f, -3.0e38f, -3.0e38f};
  float hL[3]  = {0.f, 0.f, 0.f};
  ushort_t pend[3] = {0, 0, 0};
  int tPrev = 0;

  for (int i = tid; i < 2 * 16 * 136; i += 512) ((ushort_t*)hbuf)[i] = 0;

  // coalesced chunk stage: tile tt=(ts,kt) -> Abuf[tt*512 + lane*8]
  auto stageA = [&](int chunk) {
#pragma unroll
    for (int i = 0; i < NI; i++) {
      int tt = i * 8 + wave;
      if ((NTILE & 7) == 0 || tt < NTILE) {
        int ts = tt / KT, kt = tt - ts * KT;
        int t = dir ? 49 - (chunk * 5 + ts) : (chunk * 5 + ts);
        gload16(Xprev + ((size_t)t * 1280 + s0 + rowc) * K + kt * 32 + c4s * 8,
                Abuf + tt * 512 + lane * 8);
      }
    }
  };

  stageA(0);
  __syncthreads();                      // A0 + hbuf zero visible

  for (int chunk = 0; chunk < 10; chunk++) {
    // ---- chunk xg GEMM: accx[ts][n] = bias + x_t @ Wih ----
    float4v accx[5][4];
#pragma unroll
    for (int ts = 0; ts < 5; ts++)
#pragma unroll
      for (int n = 0; n < 4; n++)
        accx[ts][n] = float4v{biasv[n], biasv[n], biasv[n], biasv[n]};
#pragma unroll
    for (int kt = 0; kt < KT; kt++) {
      short8 Bx[4];
#pragma unroll
      for (int n = 0; n < 4; n++)
        Bx[n] = *(const short8*)(WihT + ((size_t)dir * 512 + colv[n]) * K + kt * 32 + quad * 8);
#pragma unroll
      for (int ts = 0; ts < 5; ts++) {
        short8 Ax = *(const short8*)(Abuf + (ts * KT + kt) * 512 + cl * 32 + ((quad ^ (cl & 3)) * 8));
#pragma unroll
        for (int n = 0; n < 4; n++)
          accx[ts][n] = __builtin_amdgcn_mfma_f32_16x16x32_bf16(Ax, Bx[n], accx[ts][n], 0, 0, 0);
      }
    }
    __syncthreads();                    // all waves done reading Abuf
    if (chunk < 9) stageA(chunk + 1);   // retires under the 5 steps

    // ---- 5 recurrence steps ----
#pragma unroll
    for (int ts = 0; ts < 5; ts++) {
      const int step = chunk * 5 + ts;
      const int cur = step & 1;
      const int t = dir ? 49 - step : step;

      if (MODE == 0 && step > 0) {      // flush previous step's Y (coalesced)
#pragma unroll
        for (int j = 0; j < 2; j++) {
          int c = tid + j * 512;
          Y[((size_t)tPrev * 1280 + s0 + (c >> 7)) * 256 + dir * 128 + (c & 127)] = pend[j];
        }
        if (tid < 256) {
          int c = tid + 1024;
          Y[((size_t)tPrev * 1280 + s0 + (c >> 7)) * 256 + dir * 128 + (c & 127)] = pend[2];
        }
      }

      short8 Ah[4];
#pragma unroll
      for (int kt = 0; kt < 4; kt++)    // A: m=lane&15 (=seq), k=quad*8+j
        Ah[kt] = *(const short8*)(&hbuf[cur][cl][kt * 32 + quad * 8]);
      float4v acch[4];
#pragma unroll
      for (int n = 0; n < 4; n++) acch[n] = float4v{0.f, 0.f, 0.f, 0.f};
#pragma unroll
      for (int kt = 0; kt < 4; kt++)
#pragma unroll
        for (int n = 0; n < 4; n++)
          acch[n] = __builtin_amdgcn_mfma_f32_16x16x32_bf16(Ah[kt], Bhh[n][kt], acch[n], 0, 0, 0);

#pragma unroll
      for (int n = 0; n < 4; n++)
#pragma unroll
        for (int r = 0; r < 4; r++) {
          int seq = quad * 4 + r;       // C: row=quad*4+r, col=lane&15
          if (seq < 10)
            P[((seq << 7) + hcv[n]) * 4 + gatev[n]] = acch[n][r] + accx[ts][n][r];
        }
      __syncthreads();                  // gate sums visible

      auto cellDo = [&](int c, int j) {
        float4v g4 = *(const float4v*)(P + c * 4);
        float ii = sigmoidf_(g4[0]);
        float ff = sigmoidf_(g4[1]);
        float gc = tanhf_(g4[2]);
        float oo = sigmoidf_(g4[3]);
        float c2 = ff * cst[j] + ii * gc;
        cst[j] = c2;
        float h = oo * tanhf_(c2);
        ushort_t hb = f2bf(h);
        hbuf[cur ^ 1][c >> 7][c & 127] = hb;
        if (MODE == 0) {
          pend[j] = hb;
        } else {
          sum[j] += h;
          mx[j] = fmaxf(mx[j], h);
          hL[j] = h;
        }
      };
      cellDo(tid, 0);
      cellDo(tid + 512, 1);
      if (tid < 256) cellDo(tid + 1024, 2);

      tPrev = t;
      __syncthreads();                  // h visible; P reusable
    }
  }

  if (MODE == 0) {
#pragma unroll
    for (int j = 0; j < 2; j++) {
      int c = tid + j * 512;
      Y[((size_t)tPrev * 1280 + s0 + (c >> 7)) * 256 + dir * 128 + (c & 127)] = pend[j];
    }
    if (tid < 256) {
      int c = tid + 1024;
      Y[((size_t)tPrev * 1280 + s0 + (c >> 7)) * 256 + dir * 128 + (c & 127)] = pend[2];
    }
  } else {
    auto aggDo = [&](int c, int j) {
      int seq = s0 + (c >> 7), cc = dir * 128 + (c & 127);
      aggb[(size_t)seq * 768 + cc]       = f2bf(sum[j] * (1.0f / 50.0f));
      aggb[(size_t)seq * 768 + 256 + cc] = f2bf(mx[j]);
      aggb[(size_t)seq * 768 + 512 + cc] = f2bf(hL[j]);   // h_n of this dir
    };
    aggDo(tid, 0);
    aggDo(tid + 512, 1);
    if (tid < 256) aggDo(tid + 1024, 2);
  }
}

// --------------------------- fused head -------------------------------------
__global__ __launch_bounds__(512, 1) void k_head(
    const ushort_t* __restrict__ aggb,  // [1280][768] bf16
    const ushort_t* __restrict__ W1T,   // [512][768] bf16
    const float* __restrict__ b1, const float* __restrict__ ln_g,
    const float* __restrict__ ln_b,
    const ushort_t* __restrict__ W2T,   // [256][512] bf16
    const float* __restrict__ b2, float* __restrict__ out) // [1280][256]
{
  __shared__ __align__(16) char smem[78336];
  ushort_t* AsB = (ushort_t*)smem;            // [2][64*32]   (8 KiB)
  ushort_t* BsB = (ushort_t*)(smem + 8192);   // [2][512*32]  (64 KiB)
  ushort_t* hn  = (ushort_t*)smem;            // [64][520] aliased (66.6 KiB)
  float* partS  = (float*)(smem + 73728);     // [64][8]
  float* partQ  = partS + 512;                // [64][8]
  float* muS    = partQ + 512;                // [64]
  float* rsS    = muS + 64;                   // [64]

  const int m0 = blockIdx.x * 64;
  const int tid = threadIdx.x;
  const int wave = tid >> 6, lane = tid & 63;
  const int cl = lane & 15, quad = lane >> 4;
  const int srow = lane >> 2, scol = (lane & 3) * 8;

  float4v acc1[4][4];
#pragma unroll
  for (int i = 0; i < 4; i++)
#pragma unroll
    for (int v = 0; v < 4; v++) acc1[i][v] = float4v{0.f, 0.f, 0.f, 0.f};

#define STAGE1(buf, kb)                                                       \
  {                                                                           \
    if (wave < 4)                                                             \
      gload16(aggb + (size_t)(m0 + wave * 16 + srow) * 768 + (kb) + scol,     \
              AsB + (buf) * 2048 + wave * 16 * 32 + lane * 8);                \
    _Pragma("unroll")                                                         \
    for (int j = 0; j < 4; j++)                                               \
      gload16(W1T + (size_t)(wave * 64 + j * 16 + srow) * 768 + (kb) + scol,  \
              BsB + (buf) * 16384 + (wave * 64 + j * 16) * 32 + lane * 8);    \
  }

  STAGE1(0, 0)
  for (int kb = 0; kb < 768; kb += 32) {
    const int cur = (kb >> 5) & 1;
    __syncthreads();
    if (kb + 32 < 768) STAGE1(cur ^ 1, kb + 32)
    short8 Af[4], Bf[4];
#pragma unroll
    for (int i = 0; i < 4; i++)
      Af[i] = *(const short8*)(AsB + cur * 2048 + (i * 16 + cl) * 32 + quad * 8);
#pragma unroll
    for (int v = 0; v < 4; v++)
      Bf[v] = *(const short8*)(BsB + cur * 16384 + (wave * 64 + v * 16 + cl) * 32 + quad * 8);
#pragma unroll
    for (int i = 0; i < 4; i++)
#pragma unroll
      for (int v = 0; v < 4; v++)
        acc1[i][v] = __builtin_amdgcn_mfma_f32_16x16x32_bf16(Af[i], Bf[v], acc1[i][v], 0, 0, 0);
  }
#undef STAGE1
  __syncthreads();          // all waves done with AsB/BsB (hn aliases them)

  float bcol[4], lg[4], lb[4];
#pragma unroll
  for (int v = 0; v < 4; v++) {
    int col = wave * 64 + v * 16 + cl;
    bcol[v] = b1[col]; lg[v] = ln_g[col]; lb[v] = ln_b[col];
  }

#pragma unroll
  for (int i = 0; i < 4; i++) {
#pragma unroll
    for (int r = 0; r < 4; r++) {
      float s = 0.f, q = 0.f;
#pragma unroll
      for (int v = 0; v < 4; v++) {
        float x = acc1[i][v][r] + bcol[v];
        s += x; q += x * x;
      }
#pragma unroll
      for (int m = 1; m <= 8; m <<= 1) {
        s += __shfl_xor(s, m);
        q += __shfl_xor(q, m);
      }
      if (cl == 0) {
        int row = i * 16 + quad * 4 + r;
        partS[row * 8 + wave] = s;
        partQ[row * 8 + wave] = q;
      }
    }
  }
  __syncthreads();
  if (tid < 64) {
    float s = 0.f, q = 0.f;
#pragma unroll
    for (int w = 0; w < 8; w++) { s += partS[tid * 8 + w]; q += partQ[tid * 8 + w]; }
    float mu = s * (1.0f / 512.0f);
    float var = q * (1.0f / 512.0f) - mu * mu;
    muS[tid] = mu;
    rsS[tid] = rsqrtf(var + 1e-5f);
  }
  __syncthreads();

#pragma unroll
  for (int i = 0; i < 4; i++) {
#pragma unroll
    for (int r = 0; r < 4; r++) {
      int row = i * 16 + quad * 4 + r;
      float mu = muS[row], rs = rsS[row];
#pragma unroll
      for (int v = 0; v < 4; v++) {
        int col = wave * 64 + v * 16 + cl;
        float x = acc1[i][v][r] + bcol[v];
        float y = (x - mu) * rs * lg[v] + lb[v];
        hn[row * 520 + col] = f2bf(fmaxf(y, 0.0f));
      }
    }
  }
  __syncthreads();

  float4v acc2[4][2];
#pragma unroll
  for (int i = 0; i < 4; i++)
#pragma unroll
    for (int u = 0; u < 2; u++) acc2[i][u] = float4v{0.f, 0.f, 0.f, 0.f};
  for (int kt = 0; kt < 16; kt++) {
    short8 Af2[4], Bf2[2];
#pragma unroll
    for (int u = 0; u < 2; u++)
      Bf2[u] = *(const short8*)(W2T + (size_t)(wave * 32 + u * 16 + cl) * 512 + kt * 32 + quad * 8);
#pragma unroll
    for (int i = 0; i < 4; i++)
      Af2[i] = *(const short8*)(hn + (i * 16 + cl) * 520 + kt * 32 + quad * 8);
#pragma unroll
    for (int i = 0; i < 4; i++)
#pragma unroll
      for (int u = 0; u < 2; u++)
        acc2[i][u] = __builtin_amdgcn_mfma_f32_16x16x32_bf16(Af2[i], Bf2[u], acc2[i][u], 0, 0, 0);
  }
#pragma unroll
  for (int u = 0; u < 2; u++) {
    int col = wave * 32 + u * 16 + cl;
    float bb = b2[col];
#pragma unroll
    for (int i = 0; i < 4; i++)
#pragma unroll
      for (int r = 0; r < 4; r++)
        out[(size_t)(m0 + i * 16 + quad * 4 + r) * 256 + col] = acc2[i][u][r] + bb;
  }
}

// --------------------------- launcher --------------------------------------
extern "C" void kernel_launch(void* const* d_in, const int* in_sizes, int n_in,
                              void* d_out, int out_size, void* d_ws, size_t ws_size,
                              hipStream_t stream)
{
  (void)in_sizes; (void)n_in; (void)out_size; (void)ws_size;
  const float* imu   = (const float*)d_in[0];
  const float* W_in  = (const float*)d_in[1];
  const float* b_in  = (const float*)d_in[2];
  const float* Wih0  = (const float*)d_in[3];
  const float* Whh0  = (const float*)d_in[4];
  const float* bih0  = (const float*)d_in[5];
  const float* bhh0  = (const float*)d_in[6];
  const float* Wih1  = (const float*)d_in[7];
  const float* Whh1  = (const float*)d_in[8];
  const float* bih1  = (const float*)d_in[9];
  const float* bhh1  = (const float*)d_in[10];
  const float* Wih2  = (const float*)d_in[11];
  const float* Whh2  = (const float*)d_in[12];
  const float* bih2  = (const float*)d_in[13];
  const float* bhh2  = (const float*)d_in[14];
  const float* Wout1 = (const float*)d_in[15];
  const float* bout1 = (const float*)d_in[16];
  const float* ln_g  = (const float*)d_in[17];
  const float* ln_b  = (const float*)d_in[18];
  const float* Wout2 = (const float*)d_in[19];
  const float* bout2 = (const float*)d_in[20];
  float* out = (float*)d_out;
  char* ws = (char*)d_ws;

  // ws layout (bytes): act0 @0 (8.19 MB) | Ya @8192000 (32.77 MB)
  //                  | Yb @40960000 (32.77 MB) | WT @73728000 (3.01 MB)
  // aggb reuses act0 region (act0 dead after layer 0; aggb written layer 2).
  ushort_t* act0 = (ushort_t*)(ws + 0);
  ushort_t* Ya   = (ushort_t*)(ws + 8192000);
  ushort_t* Yb   = (ushort_t*)(ws + 40960000);
  ushort_t* WT   = (ushort_t*)(ws + 73728000);
  ushort_t* aggb = (ushort_t*)(ws + 0);

  ushort_t* WT_ih0 = WT + 0;
  ushort_t* WT_ih1 = WT + 65536;
  ushort_t* WT_ih2 = WT + 327680;
  ushort_t* WT_hh0 = WT + 589824;
  ushort_t* WT_hh1 = WT + 720896;
  ushort_t* WT_hh2 = WT + 851968;
  ushort_t* W1T    = WT + 983040;
  ushort_t* W2T    = WT + 1376256;

  k_prep<<<736, 256, 0, stream>>>(Wih0, Wih1, Wih2, Whh0, Whh1, Whh2,
                                  Wout1, Wout2, WT);
  k_inproj<<<16000, 256, 0, stream>>>(imu, W_in, b_in, act0);

  k_fscan<64, 0><<<dim3(128, 2), 512, 0, stream>>>(
      act0, WT_ih0, WT_hh0, bih0, bhh0, Ya, aggb);
  k_fscan<256, 0><<<dim3(128, 2), 512, 0, stream>>>(
      Ya, WT_ih1, WT_hh1, bih1, bhh1, Yb, aggb);
  k_fscan<256, 1><<<dim3(128, 2), 512, 0, stream>>>(
      Yb, WT_ih2, WT_hh2, bih2, bhh2, Ya, aggb);

  k_head<<<20, 512, 0, stream>>>(aggb, W1T, bout1, ln_g, ln_b, W2T, bout2, out);
}

// Round 8
// 1087.663 us; speedup vs baseline: 1.1227x; 1.0562x over previous
//
#include <hip/hip_runtime.h>
#include <stdint.h>

// ---------------------------------------------------------------------------
// TimeAwareIMULSTMEncoder on MI355X (gfx950) — round 8
// vs round 7 (fusion kept; L2-residency + LDS-conflict fixes):
//  * Y stores non-temporal (__builtin_nontemporal_store) and Xprev staging
//    DMA aux=NT: streaming traffic no longer evicts WihT from per-XCD L2.
//    Round 7 showed 536 MB HBM fetch ~= WihT slice (256 KB) re-missed per
//    block per chunk (655 MB requested) because Y/Xprev streams thrash L2.
//  * P gate-exchange layout [gate][seq(132)][hc]: write 2-way banks (free),
//    read stride-1 (free). Round 7: 10.6M conflict-cycles/dispatch.
// ---------------------------------------------------------------------------

typedef unsigned short ushort_t;
typedef short short8 __attribute__((ext_vector_type(8)));     // 8 bf16 (4 VGPRs)
typedef float float4v __attribute__((ext_vector_type(4)));    // MFMA acc

#define DEV_INLINE __device__ __forceinline__

DEV_INLINE ushort_t f2bf(float f) {                 // RNE f32 -> bf16 bits
  union { float f; unsigned u; } v; v.f = f;
  unsigned r = v.u + 0x7fffu + ((v.u >> 16) & 1u);
  return (ushort_t)(r >> 16);
}
DEV_INLINE float bf2f(ushort_t s) {
  union { unsigned u; float f; } v; v.u = ((unsigned)s) << 16;
  return v.f;
}
DEV_INLINE float sigmoidf_(float x) {
  return __builtin_amdgcn_rcpf(1.0f + __expf(-x));
}
DEV_INLINE float tanhf_(float x) {                  // 1 - 2/(1+e^{2x}); safe at +-inf
  return 1.0f - 2.0f * __builtin_amdgcn_rcpf(1.0f + __expf(2.0f * x));
}

// async global->LDS, 16B per lane; dst must be wave-uniform base + lane*16.
DEV_INLINE void gload16(const ushort_t* g, ushort_t* l) {
  __builtin_amdgcn_global_load_lds(
      (const __attribute__((address_space(1))) unsigned int*)g,
      (__attribute__((address_space(3))) unsigned int*)l, 16, 0, 0);
}
// NT variant: CPol NT bit (=2 on gfx94x/gfx950) — evict-first in L2.
DEV_INLINE void gload16nt(const ushort_t* g, ushort_t* l) {
  __builtin_amdgcn_global_load_lds(
      (const __attribute__((address_space(1))) unsigned int*)g,
      (__attribute__((address_space(3))) unsigned int*)l, 16, 0, 2);
}

// --------------------------- weight prep (tiled transpose) ------------------
// WT arena (elements):
//   Wih0 @0 [2*512*64] | Wih1 @65536 [2*512*256] | Wih2 @327680 [2*512*256]
//   Whh0 @589824 | Whh1 @720896 | Whh2 @851968 (each [2*512*128])
//   W1T  @983040 [512*768] | W2T @1376256 [256*512]
__global__ __launch_bounds__(256) void k_prep(
    const float* __restrict__ Wih0, const float* __restrict__ Wih1,
    const float* __restrict__ Wih2, const float* __restrict__ Whh0,
    const float* __restrict__ Whh1, const float* __restrict__ Whh2,
    const float* __restrict__ Wout1, const float* __restrict__ Wout2,
    ushort_t* __restrict__ WT)
{
  __shared__ float T[32][65];
  const int b = blockIdx.x;
  const int tid = threadIdx.x;
  const float* S; int Kd, C; size_t dstBase; int kt, nt;
  if (b < 32) {
    int rel = b; int d = (rel >> 3) / 2; kt = (rel >> 3) & 1; nt = rel & 7;
    S = Wih0 + (size_t)d * 64 * 512; C = 512; Kd = 64;
    dstBase = 0 + (size_t)d * 512 * 64;
  } else if (b < 160) {
    int rel = b - 32; int d = (rel >> 3) / 8; kt = (rel >> 3) & 7; nt = rel & 7;
    S = Wih1 + (size_t)d * 256 * 512; C = 512; Kd = 256;
    dstBase = 65536 + (size_t)d * 512 * 256;
  } else if (b < 288) {
    int rel = b - 160; int d = (rel >> 3) / 8; kt = (rel >> 3) & 7; nt = rel & 7;
    S = Wih2 + (size_t)d * 256 * 512; C = 512; Kd = 256;
    dstBase = 327680 + (size_t)d * 512 * 256;
  } else if (b < 352) {
    int rel = b - 288; int d = (rel >> 3) / 4; kt = (rel >> 3) & 3; nt = rel & 7;
    S = Whh0 + (size_t)d * 128 * 512; C = 512; Kd = 128;
    dstBase = 589824 + (size_t)d * 512 * 128;
  } else if (b < 416) {
    int rel = b - 352; int d = (rel >> 3) / 4; kt = (rel >> 3) & 3; nt = rel & 7;
    S = Whh1 + (size_t)d * 128 * 512; C = 512; Kd = 128;
    dstBase = 720896 + (size_t)d * 512 * 128;
  } else if (b < 480) {
    int rel = b - 416; int d = (rel >> 3) / 4; kt = (rel >> 3) & 3; nt = rel & 7;
    S = Whh2 + (size_t)d * 128 * 512; C = 512; Kd = 128;
    dstBase = 851968 + (size_t)d * 512 * 128;
  } else if (b < 672) {
    int rel = b - 480; kt = rel >> 3; nt = rel & 7;
    S = Wout1; C = 512; Kd = 768; dstBase = 983040;
  } else {
    int rel = b - 672; kt = rel >> 2; nt = rel & 3;
    S = Wout2; C = 256; Kd = 512; dstBase = 1376256;
  }
  const int k0 = kt * 32, n0 = nt * 64;
  {
    int kr = tid >> 6;                // 0..3
    int n  = tid & 63;
#pragma unroll
    for (int i = 0; i < 8; i++)
      T[i * 4 + kr][n] = S[(size_t)(k0 + i * 4 + kr) * C + n0 + n];
  }
  __syncthreads();
  {
    int n = tid >> 2;                 // 0..63
    int ko = (tid & 3) * 8;           // 0,8,16,24
    ushort_t pk[8];
#pragma unroll
    for (int j = 0; j < 8; j++) pk[j] = f2bf(T[ko + j][n]);
    *(uint4*)(WT + dstBase + (size_t)(n0 + n) * Kd + k0 + ko) = *(uint4*)pk;
  }
}

// --------------------------- input projection (t-major out) -----------------
__global__ __launch_bounds__(256) void k_inproj(
    const float* __restrict__ imu, const float* __restrict__ W_in,
    const float* __restrict__ b_in, ushort_t* __restrict__ act0)
{
  int idx = blockIdx.x * 256 + threadIdx.x;   // 64000*64 exactly
  int j = idx & 63, r = idx >> 6;
  int seq = r / 50, l = r - seq * 50;
  const float* x = imu + (size_t)r * 6;
  float acc = b_in[j];
#pragma unroll
  for (int d = 0; d < 6; d++) acc += x[d] * W_in[d * 64 + j];
  acc += (l * (1.0f / 49.0f)) * W_in[6 * 64 + j] + W_in[7 * 64 + j]; // t, rate=1
  act0[((size_t)l * 1280 + seq) * 64 + j] = f2bf(fmaxf(acc, 0.0f));
}

// --------------------------- fused GEMM + LSTM scan -------------------------
// Block: 10 seqs of one direction, 512 thr / 8 waves, 256 blocks = 1/CU.
// Chunk of 5 steps: [A ready] -> xg GEMM (accx[5][4], A from swizzled LDS,
// Wih B-frags from L2, kept hot by NT-streaming everything else) ->
// [xg done] -> NT-DMA chunk+1 -> 5x recurrence step (h@Whh MFMA -> P
// exchange [gate][seq*132][hc] -> pointwise 2.5 cells/lane -> NT Y store).
template <int K, int MODE>
__global__ __launch_bounds__(512, 2) void k_fscan(
    const ushort_t* __restrict__ Xprev,  // [50][1280][K] bf16
    const ushort_t* __restrict__ WihT,   // [2][512][K] bf16 n-major
    const ushort_t* __restrict__ WhhT,   // [2][512][128] bf16 n-major
    const float* __restrict__ bih, const float* __restrict__ bhh, // [2][512]
    ushort_t* __restrict__ Y,            // [50][1280][256] bf16
    ushort_t* __restrict__ aggb)         // [1280][768] bf16
{
  constexpr int KT = K / 32;
  constexpr int NTILE = 5 * KT;                        // tiles per chunk
  constexpr int NI = (NTILE + 7) / 8;
  __shared__ __align__(16) ushort_t Abuf[NTILE * 512]; // K=256: 40 KiB
  __shared__ __align__(16) float P[4 * 1320];          // 21.1 KiB, [g][seq*132][hc]
  __shared__ __align__(16) ushort_t hbuf[2][16][136];  // 8.5 KiB

  const int dir = blockIdx.y;
  const int s0 = blockIdx.x * 10;
  const int tid = threadIdx.x;
  const int wave = tid >> 6, lane = tid & 63;
  const int cl = lane & 15, quad = lane >> 4;

  // staging lane map: row = lane>>2 (clamped), c4 = lane&3, swizzled source
  const int rowc = (lane >> 2) < 10 ? (lane >> 2) : 9;
  const int c4s = (lane & 3) ^ (rowc & 3);

  // wave owns gate-cols wave*64 + n*16 + cl (n = 0..3)
  int colv[4], gatev[4], hcv[4];
  float biasv[4];
  short8 Bhh[4][4];
#pragma unroll
  for (int n = 0; n < 4; n++) {
    colv[n] = wave * 64 + n * 16 + cl;
    gatev[n] = colv[n] >> 7;
    hcv[n] = colv[n] & 127;
    biasv[n] = bih[dir * 512 + colv[n]] + bhh[dir * 512 + colv[n]];
#pragma unroll
    for (int kt = 0; kt < 4; kt++)
      Bhh[n][kt] = *(const short8*)(WhhT + ((size_t)dir * 512 + colv[n]) * 128 + kt * 32 + quad * 8);
  }

  float cst[3] = {0.f, 0.f, 0.f};
  float sum[3] = {0.f, 0.f, 0.f};
  float mx[3]  = {-3.0e38f, -3.0e38f, -3.0e38f};
  float hL[3]  = {0.f, 0.f, 0.f};
  ushort_t pend[3] = {0, 0, 0};
  int tPrev = 0;

  for (int i = tid; i < 2 * 16 * 136; i += 512) ((ushort_t*)hbuf)[i] = 0;

  // coalesced chunk stage (NT): tile tt=(ts,kt) -> Abuf[tt*512 + lane*8]
  auto stageA = [&](int chunk) {
#pragma unroll
    for (int i = 0; i < NI; i++) {
      int tt = i * 8 + wave;
      if ((NTILE & 7) == 0 || tt < NTILE) {
        int ts = tt / KT, kt = tt - ts * KT;
        int t = dir ? 49 - (chunk * 5 + ts) : (chunk * 5 + ts);
        gload16nt(Xprev + ((size_t)t * 1280 + s0 + rowc) * K + kt * 32 + c4s * 8,
                  Abuf + tt * 512 + lane * 8);
      }
    }
  };

  stageA(0);
  __syncthreads();                      // A0 + hbuf zero visible

  for (int chunk = 0; chunk < 10; chunk++) {
    // ---- chunk xg GEMM: accx[ts][n] = bias + x_t @ Wih (B from L2, hot) ----
    float4v accx[5][4];
#pragma unroll
    for (int ts = 0; ts < 5; ts++)
#pragma unroll
      for (int n = 0; n < 4; n++)
        accx[ts][n] = float4v{biasv[n], biasv[n], biasv[n], biasv[n]};
#pragma unroll
    for (int kt = 0; kt < KT; kt++) {
      short8 Bx[4];
#pragma unroll
      for (int n = 0; n < 4; n++)
        Bx[n] = *(const short8*)(WihT + ((size_t)dir * 512 + colv[n]) * K + kt * 32 + quad * 8);
#pragma unroll
      for (int ts = 0; ts < 5; ts++) {
        short8 Ax = *(const short8*)(Abuf + (ts * KT + kt) * 512 + cl * 32 + ((quad ^ (cl & 3)) * 8));
#pragma unroll
        for (int n = 0; n < 4; n++)
          accx[ts][n] = __builtin_amdgcn_mfma_f32_16x16x32_bf16(Ax, Bx[n], accx[ts][n], 0, 0, 0);
      }
    }
    __syncthreads();                    // all waves done reading Abuf
    if (chunk < 9) stageA(chunk + 1);   // retires under the 5 steps

    // ---- 5 recurrence steps ----
#pragma unroll
    for (int ts = 0; ts < 5; ts++) {
      const int step = chunk * 5 + ts;
      const int cur = step & 1;
      const int t = dir ? 49 - step : step;

      if (MODE == 0 && step > 0) {      // flush previous step's Y (NT, coalesced)
#pragma unroll
        for (int j = 0; j < 2; j++) {
          int c = tid + j * 512;
          __builtin_nontemporal_store(pend[j],
              &Y[((size_t)tPrev * 1280 + s0 + (c >> 7)) * 256 + dir * 128 + (c & 127)]);
        }
        if (tid < 256) {
          int c = tid + 1024;
          __builtin_nontemporal_store(pend[2],
              &Y[((size_t)tPrev * 1280 + s0 + (c >> 7)) * 256 + dir * 128 + (c & 127)]);
        }
      }

      short8 Ah[4];
#pragma unroll
      for (int kt = 0; kt < 4; kt++)    // A: m=lane&15 (=seq), k=quad*8+j
        Ah[kt] = *(const short8*)(&hbuf[cur][cl][kt * 32 + quad * 8]);
      float4v acch[4];
#pragma unroll
      for (int n = 0; n < 4; n++) acch[n] = float4v{0.f, 0.f, 0.f, 0.f};
#pragma unroll
      for (int kt = 0; kt < 4; kt++)
#pragma unroll
        for (int n = 0; n < 4; n++)
          acch[n] = __builtin_amdgcn_mfma_f32_16x16x32_bf16(Ah[kt], Bhh[n][kt], acch[n], 0, 0, 0);

#pragma unroll
      for (int n = 0; n < 4; n++)
#pragma unroll
        for (int r = 0; r < 4; r++) {
          int seq = quad * 4 + r;       // C: row=quad*4+r, col=lane&15
          if (seq < 10)                 // banks: (16q+4r+cl)%32 -> 2-way, free
            P[gatev[n] * 1320 + seq * 132 + hcv[n]] = acch[n][r] + accx[ts][n][r];
        }
      __syncthreads();                  // gate sums visible

      auto cellDo = [&](int c, int j) {
        int ps = (c >> 7) * 132 + (c & 127);
        float gi = P[ps];
        float gf = P[1320 + ps];
        float gg = P[2640 + ps];
        float go = P[3960 + ps];
        float ii = sigmoidf_(gi);
        float ff = sigmoidf_(gf);
        float gc = tanhf_(gg);
        float oo = sigmoidf_(go);
        float c2 = ff * cst[j] + ii * gc;
        cst[j] = c2;
        float h = oo * tanhf_(c2);
        ushort_t hb = f2bf(h);
        hbuf[cur ^ 1][c >> 7][c & 127] = hb;
        if (MODE == 0) {
          pend[j] = hb;
        } else {
          sum[j] += h;
          mx[j] = fmaxf(mx[j], h);
          hL[j] = h;
        }
      };
      cellDo(tid, 0);
      cellDo(tid + 512, 1);
      if (tid < 256) cellDo(tid + 1024, 2);

      tPrev = t;
      __syncthreads();                  // h visible; P reusable
    }
  }

  if (MODE == 0) {
#pragma unroll
    for (int j = 0; j < 2; j++) {
      int c = tid + j * 512;
      __builtin_nontemporal_store(pend[j],
          &Y[((size_t)tPrev * 1280 + s0 + (c >> 7)) * 256 + dir * 128 + (c & 127)]);
    }
    if (tid < 256) {
      int c = tid + 1024;
      __builtin_nontemporal_store(pend[2],
          &Y[((size_t)tPrev * 1280 + s0 + (c >> 7)) * 256 + dir * 128 + (c & 127)]);
    }
  } else {
    auto aggDo = [&](int c, int j) {
      int seq = s0 + (c >> 7), cc = dir * 128 + (c & 127);
      aggb[(size_t)seq * 768 + cc]       = f2bf(sum[j] * (1.0f / 50.0f));
      aggb[(size_t)seq * 768 + 256 + cc] = f2bf(mx[j]);
      aggb[(size_t)seq * 768 + 512 + cc] = f2bf(hL[j]);   // h_n of this dir
    };
    aggDo(tid, 0);
    aggDo(tid + 512, 1);
    if (tid < 256) aggDo(tid + 1024, 2);
  }
}

// --------------------------- fused head -------------------------------------
__global__ __launch_bounds__(512, 1) void k_head(
    const ushort_t* __restrict__ aggb,  // [1280][768] bf16
    const ushort_t* __restrict__ W1T,   // [512][768] bf16
    const float* __restrict__ b1, const float* __restrict__ ln_g,
    const float* __restrict__ ln_b,
    const ushort_t* __restrict__ W2T,   // [256][512] bf16
    const float* __restrict__ b2, float* __restrict__ out) // [1280][256]
{
  __shared__ __align__(16) char smem[78336];
  ushort_t* AsB = (ushort_t*)smem;            // [2][64*32]   (8 KiB)
  ushort_t* BsB = (ushort_t*)(smem + 8192);   // [2][512*32]  (64 KiB)
  ushort_t* hn  = (ushort_t*)smem;            // [64][520] aliased (66.6 KiB)
  float* partS  = (float*)(smem + 73728);     // [64][8]
  float* partQ  = partS + 512;                // [64][8]
  float* muS    = partQ + 512;                // [64]
  float* rsS    = muS + 64;                   // [64]

  const int m0 = blockIdx.x * 64;
  const int tid = threadIdx.x;
  const int wave = tid >> 6, lane = tid & 63;
  const int cl = lane & 15, quad = lane >> 4;
  const int srow = lane >> 2, scol = (lane & 3) * 8;

  float4v acc1[4][4];
#pragma unroll
  for (int i = 0; i < 4; i++)
#pragma unroll
    for (int v = 0; v < 4; v++) acc1[i][v] = float4v{0.f, 0.f, 0.f, 0.f};

#define STAGE1(buf, kb)                                                       \
  {                                                                           \
    if (wave < 4)                                                             \
      gload16(aggb + (size_t)(m0 + wave * 16 + srow) * 768 + (kb) + scol,     \
              AsB + (buf) * 2048 + wave * 16 * 32 + lane * 8);                \
    _Pragma("unroll")                                                         \
    for (int j = 0; j < 4; j++)                                               \
      gload16(W1T + (size_t)(wave * 64 + j * 16 + srow) * 768 + (kb) + scol,  \
              BsB + (buf) * 16384 + (wave * 64 + j * 16) * 32 + lane * 8);    \
  }

  STAGE1(0, 0)
  for (int kb = 0; kb < 768; kb += 32) {
    const int cur = (kb >> 5) & 1;
    __syncthreads();
    if (kb + 32 < 768) STAGE1(cur ^ 1, kb + 32)
    short8 Af[4], Bf[4];
#pragma unroll
    for (int i = 0; i < 4; i++)
      Af[i] = *(const short8*)(AsB + cur * 2048 + (i * 16 + cl) * 32 + quad * 8);
#pragma unroll
    for (int v = 0; v < 4; v++)
      Bf[v] = *(const short8*)(BsB + cur * 16384 + (wave * 64 + v * 16 + cl) * 32 + quad * 8);
#pragma unroll
    for (int i = 0; i < 4; i++)
#pragma unroll
      for (int v = 0; v < 4; v++)
        acc1[i][v] = __builtin_amdgcn_mfma_f32_16x16x32_bf16(Af[i], Bf[v], acc1[i][v], 0, 0, 0);
  }
#undef STAGE1
  __syncthreads();          // all waves done with AsB/BsB (hn aliases them)

  float bcol[4], lg[4], lb[4];
#pragma unroll
  for (int v = 0; v < 4; v++) {
    int col = wave * 64 + v * 16 + cl;
    bcol[v] = b1[col]; lg[v] = ln_g[col]; lb[v] = ln_b[col];
  }

#pragma unroll
  for (int i = 0; i < 4; i++) {
#pragma unroll
    for (int r = 0; r < 4; r++) {
      float s = 0.f, q = 0.f;
#pragma unroll
      for (int v = 0; v < 4; v++) {
        float x = acc1[i][v][r] + bcol[v];
        s += x; q += x * x;
      }
#pragma unroll
      for (int m = 1; m <= 8; m <<= 1) {
        s += __shfl_xor(s, m);
        q += __shfl_xor(q, m);
      }
      if (cl == 0) {
        int row = i * 16 + quad * 4 + r;
        partS[row * 8 + wave] = s;
        partQ[row * 8 + wave] = q;
      }
    }
  }
  __syncthreads();
  if (tid < 64) {
    float s = 0.f, q = 0.f;
#pragma unroll
    for (int w = 0; w < 8; w++) { s += partS[tid * 8 + w]; q += partQ[tid * 8 + w]; }
    float mu = s * (1.0f / 512.0f);
    float var = q * (1.0f / 512.0f) - mu * mu;
    muS[tid] = mu;
    rsS[tid] = rsqrtf(var + 1e-5f);
  }
  __syncthreads();

#pragma unroll
  for (int i = 0; i < 4; i++) {
#pragma unroll
    for (int r = 0; r < 4; r++) {
      int row = i * 16 + quad * 4 + r;
      float mu = muS[row], rs = rsS[row];
#pragma unroll
      for (int v = 0; v < 4; v++) {
        int col = wave * 64 + v * 16 + cl;
        float x = acc1[i][v][r] + bcol[v];
        float y = (x - mu) * rs * lg[v] + lb[v];
        hn[row * 520 + col] = f2bf(fmaxf(y, 0.0f));
      }
    }
  }
  __syncthreads();

  float4v acc2[4][2];
#pragma unroll
  for (int i = 0; i < 4; i++)
#pragma unroll
    for (int u = 0; u < 2; u++) acc2[i][u] = float4v{0.f, 0.f, 0.f, 0.f};
  for (int kt = 0; kt < 16; kt++) {
    short8 Af2[4], Bf2[2];
#pragma unroll
    for (int u = 0; u < 2; u++)
      Bf2[u] = *(const short8*)(W2T + (size_t)(wave * 32 + u * 16 + cl) * 512 + kt * 32 + quad * 8);
#pragma unroll
    for (int i = 0; i < 4; i++)
      Af2[i] = *(const short8*)(hn + (i * 16 + cl) * 520 + kt * 32 + quad * 8);
#pragma unroll
    for (int i = 0; i < 4; i++)
#pragma unroll
      for (int u = 0; u < 2; u++)
        acc2[i][u] = __builtin_amdgcn_mfma_f32_16x16x32_bf16(Af2[i], Bf2[u], acc2[i][u], 0, 0, 0);
  }
#pragma unroll
  for (int u = 0; u < 2; u++) {
    int col = wave * 32 + u * 16 + cl;
    float bb = b2[col];
#pragma unroll
    for (int i = 0; i < 4; i++)
#pragma unroll
      for (int r = 0; r < 4; r++)
        out[(size_t)(m0 + i * 16 + quad * 4 + r) * 256 + col] = acc2[i][u][r] + bb;
  }
}

// --------------------------- launcher --------------------------------------
extern "C" void kernel_launch(void* const* d_in, const int* in_sizes, int n_in,
                              void* d_out, int out_size, void* d_ws, size_t ws_size,
                              hipStream_t stream)
{
  (void)in_sizes; (void)n_in; (void)out_size; (void)ws_size;
  const float* imu   = (const float*)d_in[0];
  const float* W_in  = (const float*)d_in[1];
  const float* b_in  = (const float*)d_in[2];
  const float* Wih0  = (const float*)d_in[3];
  const float* Whh0  = (const float*)d_in[4];
  const float* bih0  = (const float*)d_in[5];
  const float* bhh0  = (const float*)d_in[6];
  const float* Wih1  = (const float*)d_in[7];
  const float* Whh1  = (const float*)d_in[8];
  const float* bih1  = (const float*)d_in[9];
  const float* bhh1  = (const float*)d_in[10];
  const float* Wih2  = (const float*)d_in[11];
  const float* Whh2  = (const float*)d_in[12];
  const float* bih2  = (const float*)d_in[13];
  const float* bhh2  = (const float*)d_in[14];
  const float* Wout1 = (const float*)d_in[15];
  const float* bout1 = (const float*)d_in[16];
  const float* ln_g  = (const float*)d_in[17];
  const float* ln_b  = (const float*)d_in[18];
  const float* Wout2 = (const float*)d_in[19];
  const float* bout2 = (const float*)d_in[20];
  float* out = (float*)d_out;
  char* ws = (char*)d_ws;

  // ws layout (bytes): act0 @0 (8.19 MB) | Ya @8192000 (32.77 MB)
  //                  | Yb @40960000 (32.77 MB) | WT @73728000 (3.01 MB)
  // aggb reuses act0 region (act0 dead after layer 0; aggb written layer 2).
  ushort_t* act0 = (ushort_t*)(ws + 0);
  ushort_t* Ya   = (ushort_t*)(ws + 8192000);
  ushort_t* Yb   = (ushort_t*)(ws + 40960000);
  ushort_t* WT   = (ushort_t*)(ws + 73728000);
  ushort_t* aggb = (ushort_t*)(ws + 0);

  ushort_t* WT_ih0 = WT + 0;
  ushort_t* WT_ih1 = WT + 65536;
  ushort_t* WT_ih2 = WT + 327680;
  ushort_t* WT_hh0 = WT + 589824;
  ushort_t* WT_hh1 = WT + 720896;
  ushort_t* WT_hh2 = WT + 851968;
  ushort_t* W1T    = WT + 983040;
  ushort_t* W2T    = WT + 1376256;

  k_prep<<<736, 256, 0, stream>>>(Wih0, Wih1, Wih2, Whh0, Whh1, Whh2,
                                  Wout1, Wout2, WT);
  k_inproj<<<16000, 256, 0, stream>>>(imu, W_in, b_in, act0);

  k_fscan<64, 0><<<dim3(128, 2), 512, 0, stream>>>(
      act0, WT_ih0, WT_hh0, bih0, bhh0, Ya, aggb);
  k_fscan<256, 0><<<dim3(128, 2), 512, 0, stream>>>(
      Ya, WT_ih1, WT_hh1, bih1, bhh1, Yb, aggb);
  k_fscan<256, 1><<<dim3(128, 2), 512, 0, stream>>>(
      Yb, WT_ih2, WT_hh2, bih2, bhh2, Ya, aggb);

  k_head<<<20, 512, 0, stream>>>(aggb, W1T, bout1, ln_g, ln_b, W2T, bout2, out);
}

// Round 9
// 505.775 us; speedup vs baseline: 2.4144x; 2.1505x over previous
//
#include <hip/hip_runtime.h>
#include <stdint.h>

// ---------------------------------------------------------------------------
// TimeAwareIMULSTMEncoder on MI355X (gfx950) — round 9
// REVERT to round-5 structure (separate xg GEMM + scan; fusion falsified by
// r6-r8: WihT L2 re-fetch traffic is structural). One change vs round 5:
//  * k_scan xg prefetch depth 1 -> 2 steps. r5 counters: ~45 of 74 us was
//    stall (~2160 cy/step) = xg load latency not hidden by the 1-step
//    distance (waitcnt at the register rotation fires ~1 step after issue;
//    HBM latency under load ~900-2000 cy). Depth 2 gives ~2 steps of slack.
// ---------------------------------------------------------------------------

typedef unsigned short ushort_t;
typedef short short8 __attribute__((ext_vector_type(8)));     // 8 bf16 (4 VGPRs)
typedef float float4v __attribute__((ext_vector_type(4)));    // MFMA acc

#define DEV_INLINE __device__ __forceinline__

DEV_INLINE ushort_t f2bf(float f) {                 // RNE f32 -> bf16 bits
  union { float f; unsigned u; } v; v.f = f;
  unsigned r = v.u + 0x7fffu + ((v.u >> 16) & 1u);
  return (ushort_t)(r >> 16);
}
DEV_INLINE float bf2f(ushort_t s) {
  union { unsigned u; float f; } v; v.u = ((unsigned)s) << 16;
  return v.f;
}
DEV_INLINE float sigmoidf_(float x) {
  return __builtin_amdgcn_rcpf(1.0f + __expf(-x));
}
DEV_INLINE float tanhf_(float x) {                  // 1 - 2/(1+e^{2x}); safe at +-inf
  return 1.0f - 2.0f * __builtin_amdgcn_rcpf(1.0f + __expf(2.0f * x));
}

// async global->LDS, 16B per lane; dst must be wave-uniform base + lane*16.
DEV_INLINE void gload16(const ushort_t* g, ushort_t* l) {
  __builtin_amdgcn_global_load_lds(
      (const __attribute__((address_space(1))) unsigned int*)g,
      (__attribute__((address_space(3))) unsigned int*)l, 16, 0, 0);
}

// --------------------------- weight prep (tiled transpose) ------------------
__global__ __launch_bounds__(256) void k_prep(
    const float* __restrict__ Wih0, const float* __restrict__ Wih1,
    const float* __restrict__ Wih2, const float* __restrict__ Whh0,
    const float* __restrict__ Whh1, const float* __restrict__ Whh2,
    const float* __restrict__ Wout1, const float* __restrict__ Wout2,
    ushort_t* __restrict__ WT)
{
  __shared__ float T[32][65];
  const int b = blockIdx.x;
  const int tid = threadIdx.x;
  const float* S; int Kd, C; size_t dstBase; int kt, nt;
  if (b < 32) {
    int rel = b; int d = (rel >> 3) / 2; kt = (rel >> 3) & 1; nt = rel & 7;
    S = Wih0 + (size_t)d * 64 * 512; C = 512; Kd = 64;
    dstBase = 0 + (size_t)d * 512 * 64;
  } else if (b < 160) {
    int rel = b - 32; int d = (rel >> 3) / 8; kt = (rel >> 3) & 7; nt = rel & 7;
    S = Wih1 + (size_t)d * 256 * 512; C = 512; Kd = 256;
    dstBase = 65536 + (size_t)d * 512 * 256;
  } else if (b < 288) {
    int rel = b - 160; int d = (rel >> 3) / 8; kt = (rel >> 3) & 7; nt = rel & 7;
    S = Wih2 + (size_t)d * 256 * 512; C = 512; Kd = 256;
    dstBase = 327680 + (size_t)d * 512 * 256;
  } else if (b < 352) {
    int rel = b - 288; int d = (rel >> 3) / 4; kt = (rel >> 3) & 3; nt = rel & 7;
    S = Whh0 + (size_t)d * 128 * 512; C = 512; Kd = 128;
    dstBase = 589824 + (size_t)d * 512 * 128;
  } else if (b < 416) {
    int rel = b - 352; int d = (rel >> 3) / 4; kt = (rel >> 3) & 3; nt = rel & 7;
    S = Whh1 + (size_t)d * 128 * 512; C = 512; Kd = 128;
    dstBase = 720896 + (size_t)d * 512 * 128;
  } else if (b < 480) {
    int rel = b - 416; int d = (rel >> 3) / 4; kt = (rel >> 3) & 3; nt = rel & 7;
    S = Whh2 + (size_t)d * 128 * 512; C = 512; Kd = 128;
    dstBase = 851968 + (size_t)d * 512 * 128;
  } else if (b < 672) {
    int rel = b - 480; kt = rel >> 3; nt = rel & 7;
    S = Wout1; C = 512; Kd = 768; dstBase = 983040;
  } else {
    int rel = b - 672; kt = rel >> 2; nt = rel & 3;
    S = Wout2; C = 256; Kd = 512; dstBase = 1376256;
  }
  const int k0 = kt * 32, n0 = nt * 64;
  {
    int kr = tid >> 6;                // 0..3
    int n  = tid & 63;
#pragma unroll
    for (int i = 0; i < 8; i++)
      T[i * 4 + kr][n] = S[(size_t)(k0 + i * 4 + kr) * C + n0 + n];
  }
  __syncthreads();
  {
    int n = tid >> 2;                 // 0..63
    int ko = (tid & 3) * 8;           // 0,8,16,24
    ushort_t pk[8];
#pragma unroll
    for (int j = 0; j < 8; j++) pk[j] = f2bf(T[ko + j][n]);
    *(uint4*)(WT + dstBase + (size_t)(n0 + n) * Kd + k0 + ko) = *(uint4*)pk;
  }
}

// --------------------------- input projection ------------------------------
__global__ __launch_bounds__(256) void k_inproj(
    const float* __restrict__ imu, const float* __restrict__ W_in,
    const float* __restrict__ b_in, ushort_t* __restrict__ act0)
{
  int idx = blockIdx.x * 256 + threadIdx.x;   // 64000*64 exactly
  int j = idx & 63, r = idx >> 6;
  int l = r % 50;
  const float* x = imu + (size_t)r * 6;
  float acc = b_in[j];
#pragma unroll
  for (int d = 0; d < 6; d++) acc += x[d] * W_in[d * 64 + j];
  acc += (l * (1.0f / 49.0f)) * W_in[6 * 64 + j] + W_in[7 * 64 + j]; // t, rate=1
  act0[idx] = f2bf(fmaxf(acc, 0.0f));
}

// --------------------------- xg GEMM (bf16 MFMA, 64x256 tile) ---------------
template <int K>
__global__ __launch_bounds__(256, 3) void k_xg_gemm(
    const ushort_t* __restrict__ X,    // [64000][K] bf16 (m-major)
    const ushort_t* __restrict__ WT,   // [2][512][K] bf16 (n-major)
    const float* __restrict__ bih, const float* __restrict__ bhh, // [2][512]
    ushort_t* __restrict__ xg,         // [dirSlot][2][50][1280][256]
    int dirBase)
{
  __shared__ __align__(16) ushort_t As[2][64 * 32];    //  8 KiB
  __shared__ __align__(16) ushort_t Bs[2][256 * 32];   // 32 KiB
  const int dir = blockIdx.z + dirBase;
  const int gp  = blockIdx.y;
  const int m0  = blockIdx.x * 64;
  const int tid = threadIdx.x;
  const int wave = tid >> 6, lane = tid & 63;
  const int cl = lane & 15, quad = lane >> 4;
  const ushort_t* Wd = WT + ((size_t)dir * 512 + gp * 256) * K;   // 256 rows

  float4v acc[4][2][2];
#pragma unroll
  for (int i = 0; i < 4; i++)
#pragma unroll
    for (int u = 0; u < 2; u++)
#pragma unroll
      for (int q = 0; q < 2; q++) acc[i][u][q] = float4v{0.f, 0.f, 0.f, 0.f};

  const int srow = lane >> 2;         // 0..15
  const int scol = (lane & 3) * 8;    // 0,8,16,24

#define STAGE(buf, kb)                                                        \
  {                                                                           \
    gload16(X + (size_t)(m0 + wave * 16 + srow) * K + (kb) + scol,            \
            &As[buf][wave * 16 * 32] + lane * 8);                             \
    _Pragma("unroll")                                                         \
    for (int j = 0; j < 4; j++)                                               \
      gload16(Wd + (size_t)(wave * 64 + j * 16 + srow) * K + (kb) + scol,     \
              &Bs[buf][(wave * 64 + j * 16) * 32] + lane * 8);                \
  }

  STAGE(0, 0)
  for (int kb = 0; kb < K; kb += 32) {
    const int cur = (kb >> 5) & 1;
    __syncthreads();                  // drains DMA for cur; protects cur^1 reuse
    if (kb + 32 < K) STAGE(cur ^ 1, kb + 32)
    short8 Af[4], Bf[2][2];
#pragma unroll
    for (int i = 0; i < 4; i++)
      Af[i] = *(const short8*)(&As[cur][(i * 16 + cl) * 32 + quad * 8]);
#pragma unroll
    for (int u = 0; u < 2; u++)
#pragma unroll
      for (int q = 0; q < 2; q++)
        Bf[u][q] = *(const short8*)(&Bs[cur][(q * 128 + wave * 32 + u * 16 + cl) * 32 + quad * 8]);
#pragma unroll
    for (int i = 0; i < 4; i++)
#pragma unroll
      for (int u = 0; u < 2; u++)
#pragma unroll
        for (int q = 0; q < 2; q++)
          acc[i][u][q] = __builtin_amdgcn_mfma_f32_16x16x32_bf16(Af[i], Bf[u][q], acc[i][u][q], 0, 0, 0);
  }
#undef STAGE

  ushort_t* outp = xg + (size_t)blockIdx.z * 32768000ull + (size_t)gp * 16384000ull;
  const int gbase = dir * 512 + gp * 256;
#pragma unroll
  for (int u = 0; u < 2; u++) {
    const int hc = wave * 32 + u * 16 + cl;
    float b0 = bih[gbase + hc] + bhh[gbase + hc];
    float b1 = bih[gbase + 128 + hc] + bhh[gbase + 128 + hc];
#pragma unroll
    for (int i = 0; i < 4; i++) {
#pragma unroll
      for (int r = 0; r < 4; r++) {
        int m = m0 + i * 16 + quad * 4 + r;   // D: row=quad*4+r, col=lane&15
        int seq = m / 50, t = m - seq * 50;
        unsigned pk = (unsigned)f2bf(acc[i][u][0][r] + b0) |
                      ((unsigned)f2bf(acc[i][u][1][r] + b1) << 16);
        *(unsigned*)(outp + ((size_t)t * 1280 + seq) * 256 + hc * 2) = pk;
      }
    }
  }
}

// --------------------------- LSTM scan (round 9) ----------------------------
// One block = 16 seqs of one direction, 1024 thr / 16 waves.
// Phase 1: wave (gp=w>>3, hg=w&7) computes gates {gp*2, gp*2+1} for hcols
//          hg*16+cl via 8 MFMAs (Whh frags in VGPRs); writes pre-activation
//          sums to LDS P{gp}. Phase 2: 2 cells/lane pointwise.
// xg loads prefetched TWO steps ahead (the round-9 change): rotation only
// waits on loads issued 2 steps (~2x1500 cy) earlier.
template <int MODE>
__global__ __launch_bounds__(1024, 1) void k_scan(
    const ushort_t* __restrict__ xg,    // [dirSlot][2][50][1280][256]
    const ushort_t* __restrict__ WhhT,  // [2][512][128] bf16 n-major
    ushort_t* __restrict__ Y,           // [64000][256] bf16
    ushort_t* __restrict__ aggb,        // [1280][768] bf16
    int dirBase)
{
  const int dir = blockIdx.y + dirBase;
  const int s0 = blockIdx.x * 16;
  const int tid = threadIdx.x;
  const int wave = tid >> 6, lane = tid & 63;
  const int cl = lane & 15, quad = lane >> 4;
  const int gp = wave >> 3;             // gate pair: 0=(i,f) 1=(g,o)
  const int hcolw = (wave & 7) * 16 + cl;

  __shared__ __align__(16) ushort_t hbuf[2][16][136];   // 8.5 KiB
  __shared__ __align__(16) float P0[2048 * 2];          // 16 KiB (i,f sums)
  __shared__ __align__(16) float P1[2048 * 2];          // 16 KiB (g,o sums)

  // Whh^T fragments for this wave's 2 gates: 2 x 4 x short8 = 32 VGPR
  short8 Bf[2][4];
  const ushort_t* WTd = WhhT + (size_t)dir * (512 * 128);
#pragma unroll
  for (int q = 0; q < 2; q++)
#pragma unroll
    for (int kt = 0; kt < 4; kt++)
      Bf[q][kt] = *(const short8*)(WTd + ((gp * 2 + q) * 128 + hcolw) * 128 + kt * 32 + quad * 8);

  // per-lane pointwise cells: c = tid + j*1024
  int cseq[2], chcol[2];
#pragma unroll
  for (int j = 0; j < 2; j++) { int c = tid + j * 1024; cseq[j] = c >> 7; chcol[j] = c & 127; }

  float cst[2] = {0.f, 0.f};
  float sum[2] = {0.f, 0.f};
  float mx[2]  = {-3.0e38f, -3.0e38f};
  float hLast[2] = {0.f, 0.f};
  ushort_t pend[2] = {0, 0};
  int tPrev = 0;

  for (int i = tid; i < 16 * 136; i += 1024) ((ushort_t*)hbuf[0])[i] = 0;

  const ushort_t* xgp = xg + (size_t)blockIdx.y * 32768000ull;

  // prefetch pipeline: C = step s, N1 = s+1, N2 = s+2
  unsigned xifC[2], xgoC[2], xifN1[2], xgoN1[2], xifN2[2], xgoN2[2];
  {
    const int ta = dir ? 49 : 0;
    const int tb = dir ? 48 : 1;
#pragma unroll
    for (int j = 0; j < 2; j++) {
      size_t ba = ((size_t)ta * 1280 + s0 + cseq[j]) * 256 + chcol[j] * 2;
      size_t bb = ((size_t)tb * 1280 + s0 + cseq[j]) * 256 + chcol[j] * 2;
      xifC[j]  = *(const unsigned*)(xgp + ba);
      xgoC[j]  = *(const unsigned*)(xgp + 16384000u + ba);
      xifN1[j] = *(const unsigned*)(xgp + bb);
      xgoN1[j] = *(const unsigned*)(xgp + 16384000u + bb);
    }
  }
  __syncthreads();                      // hbuf zero visible

  for (int step = 0; step < 50; step++) {
    const int t = dir ? (49 - step) : step;
    const int cur = step & 1;

    // ---- phase 1 ----
    if (step < 48) {                    // issue step+2's loads (depth-2)
      const int tn = dir ? (t - 2) : (t + 2);
#pragma unroll
      for (int j = 0; j < 2; j++) {
        size_t base = ((size_t)tn * 1280 + s0 + cseq[j]) * 256 + chcol[j] * 2;
        xifN2[j] = *(const unsigned*)(xgp + base);
        xgoN2[j] = *(const unsigned*)(xgp + 16384000u + base);
      }
    }
    if (MODE == 0 && step > 0) {        // flush previous step's Y
#pragma unroll
      for (int j = 0; j < 2; j++)
        Y[((size_t)(s0 + cseq[j]) * 50 + tPrev) * 256 + dir * 128 + chcol[j]] = pend[j];
    }

    short8 Af[4];
#pragma unroll
    for (int kt = 0; kt < 4; kt++)      // A: m=lane&15, k=quad*8+j
      Af[kt] = *(const short8*)(&hbuf[cur][cl][kt * 32 + quad * 8]);

    float4v acc[2];
#pragma unroll
    for (int q = 0; q < 2; q++) acc[q] = float4v{0.f, 0.f, 0.f, 0.f};
#pragma unroll
    for (int kt = 0; kt < 4; kt++)
#pragma unroll
      for (int q = 0; q < 2; q++)
        acc[q] = __builtin_amdgcn_mfma_f32_16x16x32_bf16(Af[kt], Bf[q][kt], acc[q], 0, 0, 0);

    float* Pg = gp ? P1 : P0;
#pragma unroll
    for (int r = 0; r < 4; r++) {
      int cell = (quad * 4 + r) * 128 + hcolw;
      *(float2*)(Pg + cell * 2) = make_float2(acc[0][r], acc[1][r]);
    }
    __syncthreads();                    // gate sums visible

    // ---- phase 2 ----
#pragma unroll
    for (int j = 0; j < 2; j++) {
      int c = tid + j * 1024;
      float2 a0 = *(const float2*)(P0 + c * 2);
      float2 a1 = *(const float2*)(P1 + c * 2);
      float gi = a0.x + bf2f((ushort_t)(xifC[j] & 0xffff));
      float gf = a0.y + bf2f((ushort_t)(xifC[j] >> 16));
      float gg = a1.x + bf2f((ushort_t)(xgoC[j] & 0xffff));
      float go = a1.y + bf2f((ushort_t)(xgoC[j] >> 16));
      float ii = sigmoidf_(gi);
      float ff = sigmoidf_(gf);
      float gc = tanhf_(gg);
      float oo = sigmoidf_(go);
      float c2 = ff * cst[j] + ii * gc;
      cst[j] = c2;
      float h = oo * tanhf_(c2);
      ushort_t hb = f2bf(h);
      hbuf[cur ^ 1][cseq[j]][chcol[j]] = hb;
      if (MODE == 0) {
        pend[j] = hb;
      } else {
        sum[j] += h;
        mx[j] = fmaxf(mx[j], h);
        hLast[j] = h;
      }
    }
    tPrev = t;
    __syncthreads();                    // h visible; P reusable
#pragma unroll
    for (int j = 0; j < 2; j++) {       // rotate: only waits on N1 (issued
      xifC[j] = xifN1[j]; xgoC[j] = xgoN1[j];   // step-1) and N2 (this step)
      xifN1[j] = xifN2[j]; xgoN1[j] = xgoN2[j];
    }
  }

  if (MODE == 0) {
#pragma unroll
    for (int j = 0; j < 2; j++)
      Y[((size_t)(s0 + cseq[j]) * 50 + tPrev) * 256 + dir * 128 + chcol[j]] = pend[j];
  } else {
#pragma unroll
    for (int j = 0; j < 2; j++) {
      const int seq = s0 + cseq[j];
      const int c = dir * 128 + chcol[j];
      aggb[(size_t)seq * 768 + c]       = f2bf(sum[j] * (1.0f / 50.0f));
      aggb[(size_t)seq * 768 + 256 + c] = f2bf(mx[j]);
      aggb[(size_t)seq * 768 + 512 + c] = f2bf(hLast[j]);   // h_n of this dir
    }
  }
}

// --------------------------- fused head -------------------------------------
__global__ __launch_bounds__(512, 1) void k_head(
    const ushort_t* __restrict__ aggb,  // [1280][768] bf16
    const ushort_t* __restrict__ W1T,   // [512][768] bf16
    const float* __restrict__ b1, const float* __restrict__ ln_g,
    const float* __restrict__ ln_b,
    const ushort_t* __restrict__ W2T,   // [256][512] bf16
    const float* __restrict__ b2, float* __restrict__ out) // [1280][256]
{
  __shared__ __align__(16) char smem[78336];
  ushort_t* AsB = (ushort_t*)smem;            // [2][64*32]   (8 KiB)
  ushort_t* BsB = (ushort_t*)(smem + 8192);   // [2][512*32]  (64 KiB)
  ushort_t* hn  = (ushort_t*)smem;            // [64][520] aliased (66.6 KiB)
  float* partS  = (float*)(smem + 73728);     // [64][8]
  float* partQ  = partS + 512;                // [64][8]
  float* muS    = partQ + 512;                // [64]
  float* rsS    = muS + 64;                   // [64]

  const int m0 = blockIdx.x * 64;
  const int tid = threadIdx.x;
  const int wave = tid >> 6, lane = tid & 63;
  const int cl = lane & 15, quad = lane >> 4;
  const int srow = lane >> 2, scol = (lane & 3) * 8;

  float4v acc1[4][4];
#pragma unroll
  for (int i = 0; i < 4; i++)
#pragma unroll
    for (int v = 0; v < 4; v++) acc1[i][v] = float4v{0.f, 0.f, 0.f, 0.f};

#define STAGE1(buf, kb)                                                       \
  {                                                                           \
    if (wave < 4)                                                             \
      gload16(aggb + (size_t)(m0 + wave * 16 + srow) * 768 + (kb) + scol,     \
              AsB + (buf) * 2048 + wave * 16 * 32 + lane * 8);                \
    _Pragma("unroll")                                                         \
    for (int j = 0; j < 4; j++)                                               \
      gload16(W1T + (size_t)(wave * 64 + j * 16 + srow) * 768 + (kb) + scol,  \
              BsB + (buf) * 16384 + (wave * 64 + j * 16) * 32 + lane * 8);    \
  }

  STAGE1(0, 0)
  for (int kb = 0; kb < 768; kb += 32) {
    const int cur = (kb >> 5) & 1;
    __syncthreads();
    if (kb + 32 < 768) STAGE1(cur ^ 1, kb + 32)
    short8 Af[4], Bf[4];
#pragma unroll
    for (int i = 0; i < 4; i++)
      Af[i] = *(const short8*)(AsB + cur * 2048 + (i * 16 + cl) * 32 + quad * 8);
#pragma unroll
    for (int v = 0; v < 4; v++)
      Bf[v] = *(const short8*)(BsB + cur * 16384 + (wave * 64 + v * 16 + cl) * 32 + quad * 8);
#pragma unroll
    for (int i = 0; i < 4; i++)
#pragma unroll
      for (int v = 0; v < 4; v++)
        acc1[i][v] = __builtin_amdgcn_mfma_f32_16x16x32_bf16(Af[i], Bf[v], acc1[i][v], 0, 0, 0);
  }
#undef STAGE1
  __syncthreads();          // all waves done with AsB/BsB (hn aliases them)

  float bcol[4], lg[4], lb[4];
#pragma unroll
  for (int v = 0; v < 4; v++) {
    int col = wave * 64 + v * 16 + cl;
    bcol[v] = b1[col]; lg[v] = ln_g[col]; lb[v] = ln_b[col];
  }

#pragma unroll
  for (int i = 0; i < 4; i++) {
#pragma unroll
    for (int r = 0; r < 4; r++) {
      float s = 0.f, q = 0.f;
#pragma unroll
      for (int v = 0; v < 4; v++) {
        float x = acc1[i][v][r] + bcol[v];
        s += x; q += x * x;
      }
#pragma unroll
      for (int m = 1; m <= 8; m <<= 1) {
        s += __shfl_xor(s, m);
        q += __shfl_xor(q, m);
      }
      if (cl == 0) {
        int row = i * 16 + quad * 4 + r;
        partS[row * 8 + wave] = s;
        partQ[row * 8 + wave] = q;
      }
    }
  }
  __syncthreads();
  if (tid < 64) {
    float s = 0.f, q = 0.f;
#pragma unroll
    for (int w = 0; w < 8; w++) { s += partS[tid * 8 + w]; q += partQ[tid * 8 + w]; }
    float mu = s * (1.0f / 512.0f);
    float var = q * (1.0f / 512.0f) - mu * mu;
    muS[tid] = mu;
    rsS[tid] = rsqrtf(var + 1e-5f);
  }
  __syncthreads();

#pragma unroll
  for (int i = 0; i < 4; i++) {
#pragma unroll
    for (int r = 0; r < 4; r++) {
      int row = i * 16 + quad * 4 + r;
      float mu = muS[row], rs = rsS[row];
#pragma unroll
      for (int v = 0; v < 4; v++) {
        int col = wave * 64 + v * 16 + cl;
        float x = acc1[i][v][r] + bcol[v];
        float y = (x - mu) * rs * lg[v] + lb[v];
        hn[row * 520 + col] = f2bf(fmaxf(y, 0.0f));
      }
    }
  }
  __syncthreads();

  float4v acc2[4][2];
#pragma unroll
  for (int i = 0; i < 4; i++)
#pragma unroll
    for (int u = 0; u < 2; u++) acc2[i][u] = float4v{0.f, 0.f, 0.f, 0.f};
  for (int kt = 0; kt < 16; kt++) {
    short8 Af2[4], Bf2[2];
#pragma unroll
    for (int u = 0; u < 2; u++)
      Bf2[u] = *(const short8*)(W2T + (size_t)(wave * 32 + u * 16 + cl) * 512 + kt * 32 + quad * 8);
#pragma unroll
    for (int i = 0; i < 4; i++)
      Af2[i] = *(const short8*)(hn + (i * 16 + cl) * 520 + kt * 32 + quad * 8);
#pragma unroll
    for (int i = 0; i < 4; i++)
#pragma unroll
      for (int u = 0; u < 2; u++)
        acc2[i][u] = __builtin_amdgcn_mfma_f32_16x16x32_bf16(Af2[i], Bf2[u], acc2[i][u], 0, 0, 0);
  }
#pragma unroll
  for (int u = 0; u < 2; u++) {
    int col = wave * 32 + u * 16 + cl;
    float bb = b2[col];
#pragma unroll
    for (int i = 0; i < 4; i++)
#pragma unroll
      for (int r = 0; r < 4; r++)
        out[(size_t)(m0 + i * 16 + quad * 4 + r) * 256 + col] = acc2[i][u][r] + bb;
  }
}

// --------------------------- launcher --------------------------------------
extern "C" void kernel_launch(void* const* d_in, const int* in_sizes, int n_in,
                              void* d_out, int out_size, void* d_ws, size_t ws_size,
                              hipStream_t stream)
{
  (void)in_sizes; (void)n_in; (void)out_size;
  const float* imu   = (const float*)d_in[0];
  const float* W_in  = (const float*)d_in[1];
  const float* b_in  = (const float*)d_in[2];
  const float* Wih0  = (const float*)d_in[3];
  const float* Whh0  = (const float*)d_in[4];
  const float* bih0  = (const float*)d_in[5];
  const float* bhh0  = (const float*)d_in[6];
  const float* Wih1  = (const float*)d_in[7];
  const float* Whh1  = (const float*)d_in[8];
  const float* bih1  = (const float*)d_in[9];
  const float* bhh1  = (const float*)d_in[10];
  const float* Wih2  = (const float*)d_in[11];
  const float* Whh2  = (const float*)d_in[12];
  const float* bih2  = (const float*)d_in[13];
  const float* bhh2  = (const float*)d_in[14];
  const float* Wout1 = (const float*)d_in[15];
  const float* bout1 = (const float*)d_in[16];
  const float* ln_g  = (const float*)d_in[17];
  const float* ln_b  = (const float*)d_in[18];
  const float* Wout2 = (const float*)d_in[19];
  const float* bout2 = (const float*)d_in[20];
  float* out = (float*)d_out;
  char* ws = (char*)d_ws;

  // ws layout (bytes)
  const size_t ACT0_OFF = 0;                      // 8,192,000  (64000*64*2)
  const size_t YA_OFF   = 8192000;                // 32,768,000 (64000*256*2)
  const size_t YB_OFF   = 40960000;               // 32,768,000
  const size_t XG_OFF   = 73728000;               // 131,072,000 (both) / 65,536,000 (serial)
  const size_t XG_BOTH  = 131072000, XG_SER = 65536000;
  const size_t WT_SZ    = 3014656;                // 1,507,328 bf16 elems
  const bool both = ws_size >= XG_OFF + XG_BOTH + WT_SZ;
  const size_t WT_OFF = XG_OFF + (both ? XG_BOTH : XG_SER);

  ushort_t* act0 = (ushort_t*)(ws + ACT0_OFF);
  ushort_t* Ya   = (ushort_t*)(ws + YA_OFF);
  ushort_t* Yb   = (ushort_t*)(ws + YB_OFF);
  ushort_t* xg   = (ushort_t*)(ws + XG_OFF);
  ushort_t* WT   = (ushort_t*)(ws + WT_OFF);
  ushort_t* aggb = (ushort_t*)(ws + 0);           // reuses act0 region (dead by then)

  ushort_t* WT_ih0 = WT + 0;
  ushort_t* WT_ih1 = WT + 65536;
  ushort_t* WT_ih2 = WT + 327680;
  ushort_t* WT_hh0 = WT + 589824;
  ushort_t* WT_hh1 = WT + 720896;
  ushort_t* WT_hh2 = WT + 851968;
  ushort_t* W1T    = WT + 983040;
  ushort_t* W2T    = WT + 1376256;

  k_prep<<<736, 256, 0, stream>>>(Wih0, Wih1, Wih2, Whh0, Whh1, Whh2,
                                  Wout1, Wout2, WT);
  k_inproj<<<16000, 256, 0, stream>>>(imu, W_in, b_in, act0);

  const int nPass = both ? 1 : 2;
  const int gz = both ? 2 : 1;

  const ushort_t* Xs[3]   = {act0, Ya, Yb};
  ushort_t* Ys[3]         = {Ya, Yb, Ya};
  const ushort_t* WTih[3] = {WT_ih0, WT_ih1, WT_ih2};
  const ushort_t* WThh[3] = {WT_hh0, WT_hh1, WT_hh2};
  const float* bihs[3]    = {bih0, bih1, bih2};
  const float* bhhs[3]    = {bhh0, bhh1, bhh2};

  for (int layer = 0; layer < 3; layer++) {
    for (int p = 0; p < nPass; p++) {
      int dirBase = both ? 0 : p;
      if (layer == 0)
        k_xg_gemm<64><<<dim3(1000, 2, gz), 256, 0, stream>>>(
            Xs[0], WTih[0], bihs[0], bhhs[0], xg, dirBase);
      else
        k_xg_gemm<256><<<dim3(1000, 2, gz), 256, 0, stream>>>(
            Xs[layer], WTih[layer], bihs[layer], bhhs[layer], xg, dirBase);
      if (layer < 2)
        k_scan<0><<<dim3(80, gz), 1024, 0, stream>>>(xg, WThh[layer], Ys[layer], aggb, dirBase);
      else
        k_scan<1><<<dim3(80, gz), 1024, 0, stream>>>(xg, WThh[layer], Ys[layer], aggb, dirBase);
    }
  }

  k_head<<<20, 512, 0, stream>>>(aggb, W1T, bout1, ln_g, ln_b, W2T, bout2, out);
}